// Round 1
// baseline (630.207 us; speedup 1.0000x reference)
//
#include <hip/hip_runtime.h>
#include <math.h>

// ---------------- problem sizes ----------------
// x:[4,64,128,128]  y_ds:[4,128,64,64]  L=4096 tokens/batch, d_model=128,
// d_inner=256, d_state=16, dt_rank=8, conv1d k=4.
#define NB 4
#define LTOK 4096
#define DM 128
#define DI 256
#define NCH 16     // scan chunks
#define TCH 256    // steps per chunk

// ---------------- workspace layout (float offsets) ----------------
#define OFF_WT     0u          // [64ci][9tap][128co] conv weights * bn_inv   (73728)
#define OFF_BIAS2  73728u      // folded conv+bn bias [128]
#define OFF_XWT    73856u      // xproj_w transposed [256k][40e]              (10240)
#define OFF_YDS    84096u      // gelu output [4][128][64][64]               (2097152)
#define OFF_XPRE   2181248u    // [4][256][4096]                             (4194304)
#define OFF_Z      6375552u    // [4][256][4096]
#define OFF_XIN    10569856u   // [4][256][4096]
#define OFF_DELTA  14764160u   // [4][256][4096]
#define OFF_BC     18958464u   // [4][32][4096]  rows 0-15 Bm, 16-31 Cm      (524288)
#define OFF_P      19482752u   // [4096 waves][64]                           (262144)
#define OFF_S      19744896u
#define OFF_HINIT  20007040u
#define OFF_YACT   OFF_XPRE    // x_pre dead after conv1d; reuse for y_act
// total ~20.3M floats = 81 MB

#define DEV __device__ __forceinline__

// =============== K0: fold BN into conv weights; transpose xproj_w ===============
__global__ __launch_bounds__(256) void k0_prep(
    const float* __restrict__ conv_w, const float* __restrict__ conv_b,
    const float* __restrict__ bn_g, const float* __restrict__ bn_b,
    const float* __restrict__ bn_mean, const float* __restrict__ bn_var,
    const float* __restrict__ xproj_w, float* __restrict__ ws) {
  int i = blockIdx.x * 256 + threadIdx.x;
  if (i < 73728) {
    int co = i & 127; int tap = (i >> 7) % 9; int ci = i / 1152;
    float inv = bn_g[co] * rsqrtf(bn_var[co] + 1e-5f);
    ws[OFF_WT + i] = conv_w[co * 576 + ci * 9 + tap] * inv;
  } else if (i < 73728 + 10240) {
    int j = i - 73728; int e = j % 40; int k = j / 40;
    ws[OFF_XWT + j] = xproj_w[e * 256 + k];
  } else if (i < 73728 + 10240 + 128) {
    int co = i - 73728 - 10240;
    float inv = bn_g[co] * rsqrtf(bn_var[co] + 1e-5f);
    ws[OFF_BIAS2 + co] = (conv_b[co] - bn_mean[co]) * inv + bn_b[co];
  }
}

// =============== K1: conv3x3 s2 + BN + exact GELU ===============
// block = (b, oy): 64 ox lanes x 4 waves (32 c_out each). Weights via wave-uniform
// scalar loads (s_load). Input LDS split even/odd columns to kill stride-2 conflicts.
__global__ __launch_bounds__(256) void k1_conv_bn_gelu(
    const float* __restrict__ x, const float* __restrict__ wt,
    const float* __restrict__ bias2, float* __restrict__ yds) {
  __shared__ float e_lds[16][3][66];
  __shared__ float o_lds[16][3][66];
  const int tid = threadIdx.x;
  const int ox = tid & 63;
  const int wv = __builtin_amdgcn_readfirstlane(tid >> 6);
  const int oy = blockIdx.x & 63, b = blockIdx.x >> 6;
  const int iy0 = 2 * oy - 1;
  float acc[32];
#pragma unroll
  for (int j = 0; j < 32; ++j) acc[j] = 0.f;

  for (int c = 0; c < 4; ++c) {           // ci chunks of 16
    const int ci0 = c * 16;
    __syncthreads();
    for (int idx = tid; idx < 16 * 3 * 32; idx += 256) {
      int cc = idx / 96; int rem = idx % 96; int r = rem >> 5; int xq = rem & 31;
      int iy = iy0 + r;
      float4 v = make_float4(0.f, 0.f, 0.f, 0.f);
      if (iy >= 0)
        v = *(const float4*)&x[(((size_t)(b * 64 + ci0 + cc) * 128) + iy) * 128 + xq * 4];
      e_lds[cc][r][2 * xq + 0] = v.x; e_lds[cc][r][2 * xq + 1] = v.z;
      o_lds[cc][r][2 * xq + 1] = v.y; o_lds[cc][r][2 * xq + 2] = v.w;
      if (xq == 0) o_lds[cc][r][0] = 0.f;   // column -1 pad
    }
    __syncthreads();
#pragma unroll 1
    for (int cc = 0; cc < 16; ++cc) {
#pragma unroll
      for (int kh = 0; kh < 3; ++kh) {
        float v0 = o_lds[cc][kh][ox];       // kw=0 -> x[2ox-1]
        float v1 = e_lds[cc][kh][ox];       // kw=1 -> x[2ox]
        float v2 = o_lds[cc][kh][ox + 1];   // kw=2 -> x[2ox+1]
        const float* w0 = &wt[((ci0 + cc) * 9 + kh * 3 + 0) * 128 + wv * 32];
        const float* w1 = w0 + 128;
        const float* w2 = w0 + 256;
#pragma unroll
        for (int j = 0; j < 32; ++j) {
          acc[j] = fmaf(v0, w0[j], acc[j]);
          acc[j] = fmaf(v1, w1[j], acc[j]);
          acc[j] = fmaf(v2, w2[j], acc[j]);
        }
      }
    }
  }
  const int cobase = wv * 32;
#pragma unroll 4
  for (int j = 0; j < 32; ++j) {
    float v = acc[j] + bias2[cobase + j];
    float g = 0.5f * v * (1.f + erff(v * 0.70710678118f));
    yds[(((size_t)(b * 128 + cobase + j) * 64) + oy) * 64 + ox] = g;
  }
}

// =============== K2: in_proj GEMM  xz[b,e,t] = sum_k u[b,t,k]*in_w[e,k] ===============
// token tile = one spatial row (64 tokens), e-tile = 64. u read directly from yds.
__global__ __launch_bounds__(256) void k2_inproj(
    const float* __restrict__ yds, const float* __restrict__ in_w,
    float* __restrict__ xpre, float* __restrict__ z) {
  __shared__ __align__(16) float a_lds[64][68];
  __shared__ __align__(16) float w_lds[64][68];
  const int tid = threadIdx.x;
  const int et = blockIdx.x & 7;
  const int rowid = blockIdx.x >> 3;
  const int oy = rowid & 63, b = rowid >> 6;
  const int t4 = (tid & 15) * 4, e4 = (tid >> 4) * 4;
  float acc[4][4];
#pragma unroll
  for (int i = 0; i < 4; ++i)
#pragma unroll
    for (int j = 0; j < 4; ++j) acc[i][j] = 0.f;

  for (int kc = 0; kc < 2; ++kc) {
    __syncthreads();
    for (int idx = tid; idx < 1024; idx += 256) {     // a: 64k x 16 f4
      int k = idx >> 4, tq = idx & 15;
      *(float4*)&a_lds[k][tq * 4] =
          *(const float4*)&yds[(((size_t)(b * 128 + kc * 64 + k) * 64) + oy) * 64 + tq * 4];
    }
    for (int idx = tid; idx < 1024; idx += 256) {     // w: transpose to [k][e]
      int j = idx >> 4, kq = idx & 15;
      float4 v = *(const float4*)&in_w[(size_t)(et * 64 + j) * 128 + kc * 64 + kq * 4];
      w_lds[kq * 4 + 0][j] = v.x; w_lds[kq * 4 + 1][j] = v.y;
      w_lds[kq * 4 + 2][j] = v.z; w_lds[kq * 4 + 3][j] = v.w;
    }
    __syncthreads();
#pragma unroll 8
    for (int k = 0; k < 64; ++k) {
      float4 a4 = *(const float4*)&a_lds[k][t4];
      float4 b4 = *(const float4*)&w_lds[k][e4];
      float av[4] = {a4.x, a4.y, a4.z, a4.w};
      float bv[4] = {b4.x, b4.y, b4.z, b4.w};
#pragma unroll
      for (int i = 0; i < 4; ++i)
#pragma unroll
        for (int j = 0; j < 4; ++j) acc[i][j] = fmaf(av[i], bv[j], acc[i][j]);
    }
  }
  const int e0 = et * 64 + e4;
  const int tbase = oy * 64 + t4;
#pragma unroll
  for (int j = 0; j < 4; ++j) {
    int e = e0 + j;
    float4 v = make_float4(acc[0][j], acc[1][j], acc[2][j], acc[3][j]);
    float* dst = (e < 256) ? (xpre + ((size_t)(b * 256 + e) * 4096) + tbase)
                           : (z + ((size_t)(b * 256 + (e - 256)) * 4096) + tbase);
    *(float4*)dst = v;
  }
}

// =============== K3: depthwise causal conv1d (k=4) + SiLU ===============
__global__ __launch_bounds__(256) void k3_conv1d_silu(
    const float* __restrict__ xpre, const float* __restrict__ w,
    const float* __restrict__ bvec, float* __restrict__ xin) {
  int i = blockIdx.x * 256 + threadIdx.x;   // over NB*DI*1024 quads
  int tq = i & 1023; int rowd = i >> 10;    // rowd = b*256+d
  int d = rowd & 255;
  const float* base = xpre + (size_t)rowd * 4096;
  float4 cur = *(const float4*)&base[tq * 4];
  float4 prev = make_float4(0.f, 0.f, 0.f, 0.f);
  if (tq > 0) prev = *(const float4*)&base[tq * 4 - 4];
  float4 w4 = *(const float4*)&w[d * 4];
  float bias = bvec[d];
  float s[7] = {prev.y, prev.z, prev.w, cur.x, cur.y, cur.z, cur.w};
  float o[4];
#pragma unroll
  for (int j = 0; j < 4; ++j) {
    float v = bias + w4.x * s[j] + w4.y * s[j + 1] + w4.z * s[j + 2] + w4.w * s[j + 3];
    o[j] = v / (1.f + __expf(-v));
  }
  *(float4*)&xin[(size_t)rowd * 4096 + tq * 4] =
      make_float4(o[0], o[1], o[2], o[3]);
}

// =============== K4: x_proj (K=256,N=40) + dt_proj + softplus ===============
// block = 64 tokens of one batch. xproj weights via wave-uniform scalar loads.
__global__ __launch_bounds__(256) void k4_xproj_delta(
    const float* __restrict__ xin, const float* __restrict__ xwt,
    const float* __restrict__ dtw, const float* __restrict__ dtb,
    float* __restrict__ delta, float* __restrict__ bc) {
  __shared__ __align__(16) float a_lds[128][68];
  __shared__ __align__(16) float xdbl[40][68];
  const int tid = threadIdx.x;
  const int t = tid & 63;
  const int wv = __builtin_amdgcn_readfirstlane(tid >> 6);
  const int tt = blockIdx.x & 63, b = blockIdx.x >> 6;
  const int t0 = tt * 64;
  float acc[10];
#pragma unroll
  for (int j = 0; j < 10; ++j) acc[j] = 0.f;

  for (int kh2 = 0; kh2 < 2; ++kh2) {   // K staged in halves of 128 (LDS <= 64KB)
    __syncthreads();
    for (int idx = tid; idx < 2048; idx += 256) {
      int dd = idx >> 4, tq = idx & 15;
      *(float4*)&a_lds[dd][tq * 4] =
          *(const float4*)&xin[((size_t)(b * 256 + kh2 * 128 + dd) * 4096) + t0 + tq * 4];
    }
    __syncthreads();
#pragma unroll 4
    for (int k = 0; k < 128; ++k) {
      float av = a_lds[k][t];
      const float* wrow = &xwt[(kh2 * 128 + k) * 40 + wv * 10];
#pragma unroll
      for (int j = 0; j < 10; ++j) acc[j] = fmaf(av, wrow[j], acc[j]);
    }
  }
#pragma unroll
  for (int j = 0; j < 10; ++j) xdbl[wv * 10 + j][t] = acc[j];
  __syncthreads();

  // delta: thread per d; dt rows are xdbl[0..7]; direct global stores (L2 merges rows)
  {
    int d = tid;
    float4 wa = *(const float4*)&dtw[d * 8];
    float4 wb = *(const float4*)&dtw[d * 8 + 4];
    float bias = dtb[d];
    float* dst = delta + ((size_t)(b * 256 + d) * 4096) + t0;
#pragma unroll 1
    for (int tq = 0; tq < 16; ++tq) {
      float o[4];
#pragma unroll
      for (int j = 0; j < 4; ++j) {
        int tt2 = tq * 4 + j;
        float s = bias;
        s = fmaf(wa.x, xdbl[0][tt2], s); s = fmaf(wa.y, xdbl[1][tt2], s);
        s = fmaf(wa.z, xdbl[2][tt2], s); s = fmaf(wa.w, xdbl[3][tt2], s);
        s = fmaf(wb.x, xdbl[4][tt2], s); s = fmaf(wb.y, xdbl[5][tt2], s);
        s = fmaf(wb.z, xdbl[6][tt2], s); s = fmaf(wb.w, xdbl[7][tt2], s);
        o[j] = fmaxf(s, 0.f) + log1pf(__expf(-fabsf(s)));   // stable softplus
      }
      *(float4*)&dst[tq * 4] = make_float4(o[0], o[1], o[2], o[3]);
    }
  }
  // B/C rows (xdbl 8..39) -> bc, coalesced
  for (int idx = tid; idx < 512; idx += 256) {
    int m = idx >> 4, tq = idx & 15;
    *(float4*)&bc[((size_t)(b * 32 + m) * 4096) + t0 + tq * 4] =
        *(const float4*)&xdbl[8 + m][tq * 4];
  }
}

// =============== scan helpers ===============
template <int CTRL>
DEV float dpp_add(float v) {
  int s = __builtin_amdgcn_update_dpp(0, __float_as_int(v), CTRL, 0xF, 0xF, true);
  return v + __int_as_float(s);
}

// wave = 4 d x 16 n (lane = dq*16+n). Global wave id W = b*1024 + dgrp*16 + chunk.
// =============== K5a: chunk scan pass 1 -> P = prod(dA), S = h(chunk, h0=0) ===============
__global__ __launch_bounds__(256) void k5a_scan1(
    const float* __restrict__ delta, const float* __restrict__ xin,
    const float* __restrict__ bc, const float* __restrict__ A_log,
    float* __restrict__ Pb, float* __restrict__ Sb) {
  const int tid = threadIdx.x;
  const int lane = tid & 63;
  const int W = blockIdx.x * 4 + (tid >> 6);
  const int chunk = W & 15, dgrp = (W >> 4) & 63, b = W >> 10;
  const int n = lane & 15, dq = lane >> 4;
  const int d = dgrp * 4 + dq;
  const int t0 = chunk * TCH;
  const float A2 = -expf(A_log[d * 16 + n]) * 1.44269504089f;
  const float* pd = delta + ((size_t)(b * 256 + d) * 4096) + t0;
  const float* px = xin + ((size_t)(b * 256 + d) * 4096) + t0;
  const float* pb = bc + ((size_t)(b * 32 + n) * 4096) + t0;
  float h = 0.f, P = 1.f;
#pragma unroll 8
  for (int i = 0; i < TCH; ++i) {
    float dl = pd[i];
    float dA = exp2f(dl * A2);
    h = fmaf(dA, h, (dl * px[i]) * pb[i]);
    P *= dA;
  }
  int idx = W * 64 + lane;
  Pb[idx] = P; Sb[idx] = h;
}

// =============== K5b: thread chunk boundaries ===============
__global__ __launch_bounds__(256) void k5b_combine(
    const float* __restrict__ Pb, const float* __restrict__ Sb,
    float* __restrict__ hinit) {
  int ti = blockIdx.x * 256 + threadIdx.x;   // (b*64+dgrp)*64 + lane
  int lane = ti & 63; int grp = ti >> 6;
  int b = grp >> 6; int dgrp = grp & 63;
  float h = 0.f;
#pragma unroll 1
  for (int c = 0; c < NCH; ++c) {
    int idx = (b * 1024 + dgrp * 16 + c) * 64 + lane;
    hinit[idx] = h;
    h = fmaf(Pb[idx], h, Sb[idx]);
  }
}

// =============== K5c: pass 2 -> y, fused with (+x*Dp)*silu(z) epilogue ===============
__global__ __launch_bounds__(256) void k5c_scan2(
    const float* __restrict__ delta, const float* __restrict__ xin,
    const float* __restrict__ bc, const float* __restrict__ z,
    const float* __restrict__ A_log, const float* __restrict__ Dp,
    const float* __restrict__ hinit, float* __restrict__ yact) {
  const int tid = threadIdx.x;
  const int lane = tid & 63;
  const int W = blockIdx.x * 4 + (tid >> 6);
  const int chunk = W & 15, dgrp = (W >> 4) & 63, b = W >> 10;
  const int n = lane & 15, dq = lane >> 4;
  const int d = dgrp * 4 + dq;
  const int t0 = chunk * TCH;
  const float A2 = -expf(A_log[d * 16 + n]) * 1.44269504089f;
  const float Dpd = Dp[d];
  const size_t rowd = (size_t)(b * 256 + d) * 4096;
  const float* pd = delta + rowd + t0;
  const float* px = xin + rowd + t0;
  const float* pz = z + rowd + t0;
  const float* pb = bc + ((size_t)(b * 32 + n) * 4096) + t0;
  const float* pc = bc + ((size_t)(b * 32 + 16 + n) * 4096) + t0;
  float* py = yact + rowd + t0;
  float h = hinit[W * 64 + lane];
#pragma unroll 4
  for (int i = 0; i < TCH; ++i) {
    float dl = pd[i];
    float xv = px[i];
    float dA = exp2f(dl * A2);
    h = fmaf(dA, h, (dl * xv) * pb[i]);
    float p = h * pc[i];
    p = dpp_add<0x128>(p);   // row_ror:8
    p = dpp_add<0x124>(p);   // row_ror:4
    p = dpp_add<0x122>(p);   // row_ror:2
    p = dpp_add<0x121>(p);   // row_ror:1 -> full sum over 16 n-lanes
    float zv = pz[i];
    float sil = zv / (1.f + __expf(-zv));
    float yv = (p + xv * Dpd) * sil;
    if (n == 0) py[i] = yv;
  }
}

// =============== K6: out_proj GEMM + residual, writes NCHW output ===============
__global__ __launch_bounds__(256) void k6_outproj(
    const float* __restrict__ yact, const float* __restrict__ out_w,
    const float* __restrict__ yds, float* __restrict__ out) {
  __shared__ __align__(16) float a_lds[64][68];
  __shared__ __align__(16) float w_lds[64][132];
  const int tid = threadIdx.x;
  const int oy = blockIdx.x & 63, b = blockIdx.x >> 6;
  const int t4 = (tid & 15) * 4, c8 = (tid >> 4) * 8;
  float acc[4][8];
#pragma unroll
  for (int i = 0; i < 4; ++i)
#pragma unroll
    for (int j = 0; j < 8; ++j) acc[i][j] = 0.f;

  for (int kc = 0; kc < 4; ++kc) {
    __syncthreads();
    for (int idx = tid; idx < 1024; idx += 256) {
      int k = idx >> 4, tq = idx & 15;
      *(float4*)&a_lds[k][tq * 4] =
          *(const float4*)&yact[((size_t)(b * 256 + kc * 64 + k) * 4096) + oy * 64 + tq * 4];
    }
    for (int idx = tid; idx < 2048; idx += 256) {
      int cc = idx >> 4, kq = idx & 15;
      float4 v = *(const float4*)&out_w[(size_t)cc * 256 + kc * 64 + kq * 4];
      w_lds[kq * 4 + 0][cc] = v.x; w_lds[kq * 4 + 1][cc] = v.y;
      w_lds[kq * 4 + 2][cc] = v.z; w_lds[kq * 4 + 3][cc] = v.w;
    }
    __syncthreads();
#pragma unroll 4
    for (int k = 0; k < 64; ++k) {
      float4 a4 = *(const float4*)&a_lds[k][t4];
      float4 b0 = *(const float4*)&w_lds[k][c8];
      float4 b1 = *(const float4*)&w_lds[k][c8 + 4];
      float av[4] = {a4.x, a4.y, a4.z, a4.w};
      float bv[8] = {b0.x, b0.y, b0.z, b0.w, b1.x, b1.y, b1.z, b1.w};
#pragma unroll
      for (int i = 0; i < 4; ++i)
#pragma unroll
        for (int j = 0; j < 8; ++j) acc[i][j] = fmaf(av[i], bv[j], acc[i][j]);
    }
  }
#pragma unroll
  for (int j = 0; j < 8; ++j) {
    int cc = c8 + j;
    size_t base = (((size_t)(b * 128 + cc) * 64) + oy) * 64 + t4;
    float4 r = *(const float4*)&yds[base];
    *(float4*)&out[base] = make_float4(acc[0][j] + r.x, acc[1][j] + r.y,
                                       acc[2][j] + r.z, acc[3][j] + r.w);
  }
}

// =============== launch ===============
extern "C" void kernel_launch(void* const* d_in, const int* in_sizes, int n_in,
                              void* d_out, int out_size, void* d_ws, size_t ws_size,
                              hipStream_t stream) {
  (void)in_sizes; (void)n_in; (void)out_size; (void)ws_size;
  const float* x        = (const float*)d_in[0];
  const float* conv_w   = (const float*)d_in[1];
  const float* conv_b   = (const float*)d_in[2];
  const float* bn_g     = (const float*)d_in[3];
  const float* bn_b     = (const float*)d_in[4];
  const float* bn_mean  = (const float*)d_in[5];
  const float* bn_var   = (const float*)d_in[6];
  const float* in_w     = (const float*)d_in[7];
  const float* conv1d_w = (const float*)d_in[8];
  const float* conv1d_b = (const float*)d_in[9];
  const float* xproj_w  = (const float*)d_in[10];
  const float* dtproj_w = (const float*)d_in[11];
  const float* dtproj_b = (const float*)d_in[12];
  const float* A_log    = (const float*)d_in[13];
  const float* Dp       = (const float*)d_in[14];
  const float* out_w    = (const float*)d_in[15];
  float* ws = (float*)d_ws;
  float* out = (float*)d_out;

  k0_prep<<<329, 256, 0, stream>>>(conv_w, conv_b, bn_g, bn_b, bn_mean, bn_var,
                                   xproj_w, ws);
  k1_conv_bn_gelu<<<256, 256, 0, stream>>>(x, ws + OFF_WT, ws + OFF_BIAS2,
                                           ws + OFF_YDS);
  k2_inproj<<<2048, 256, 0, stream>>>(ws + OFF_YDS, in_w, ws + OFF_XPRE, ws + OFF_Z);
  k3_conv1d_silu<<<4096, 256, 0, stream>>>(ws + OFF_XPRE, conv1d_w, conv1d_b,
                                           ws + OFF_XIN);
  k4_xproj_delta<<<256, 256, 0, stream>>>(ws + OFF_XIN, ws + OFF_XWT, dtproj_w,
                                          dtproj_b, ws + OFF_DELTA, ws + OFF_BC);
  k5a_scan1<<<1024, 256, 0, stream>>>(ws + OFF_DELTA, ws + OFF_XIN, ws + OFF_BC,
                                      A_log, ws + OFF_P, ws + OFF_S);
  k5b_combine<<<64, 256, 0, stream>>>(ws + OFF_P, ws + OFF_S, ws + OFF_HINIT);
  k5c_scan2<<<1024, 256, 0, stream>>>(ws + OFF_DELTA, ws + OFF_XIN, ws + OFF_BC,
                                      ws + OFF_Z, A_log, Dp, ws + OFF_HINIT,
                                      ws + OFF_YACT);
  k6_outproj<<<256, 256, 0, stream>>>(ws + OFF_YACT, out_w, ws + OFF_YDS, out);
}

// Round 2
// 468.254 us; speedup vs baseline: 1.3459x; 1.3459x over previous
//
#include <hip/hip_runtime.h>
#include <math.h>

// ---------------- problem sizes ----------------
#define NB 4
#define LTOK 4096
#define DM 128
#define DI 256
#define NCH 32     // scan chunks
#define TCH 128    // steps per chunk

// ---------------- workspace layout (float offsets) ----------------
// all mamba intermediates are t-major: [b][t][e]
#define OFF_WT     0u          // [64ci][9tap][128co] conv weights * bn_inv (73728)
#define OFF_BIAS2  73728u      // folded conv+bn bias [128]
#define OFF_XWT    73856u      // xproj_w transposed [256k][40e] (10240)
#define OFF_YDS    84096u      // gelu output [4][128][64][64]  (2097152)
#define OFF_XPRE   2181248u    // [4][4096][256]
#define OFF_Z      6375552u    // [4][4096][256]
#define OFF_XIN    10569856u   // [4][4096][256]
#define OFF_DELTA  14764160u   // [4][4096][256]
#define OFF_BC     18958464u   // [4][4096][32]  cols 0-15 B, 16-31 C (524288)
#define OFF_S      19482752u   // [4][32c][256d][16n] (524288); reused as hinit
#define OFF_DSUM   20007040u   // [4][32c][256d] (32768)
#define OFF_YACT   OFF_XPRE    // xpre dead after conv1d; reuse
// total 20039808 floats = 80.2 MB (<= proven 81 MB budget)

#define DEV __device__ __forceinline__
#define L2E 1.4426950408889634f

DEV float fast_silu(float v) {
  return v * __builtin_amdgcn_rcpf(1.f + __expf(-v));
}

// =============== K0: fold BN into conv weights; transpose xproj_w ===============
__global__ __launch_bounds__(256) void k0_prep(
    const float* __restrict__ conv_w, const float* __restrict__ conv_b,
    const float* __restrict__ bn_g, const float* __restrict__ bn_b,
    const float* __restrict__ bn_mean, const float* __restrict__ bn_var,
    const float* __restrict__ xproj_w, float* __restrict__ ws) {
  int i = blockIdx.x * 256 + threadIdx.x;
  if (i < 73728) {
    int co = i & 127; int tap = (i >> 7) % 9; int ci = i / 1152;
    float inv = bn_g[co] * rsqrtf(bn_var[co] + 1e-5f);
    ws[OFF_WT + i] = conv_w[co * 576 + ci * 9 + tap] * inv;
  } else if (i < 73728 + 10240) {
    int j = i - 73728; int e = j % 40; int k = j / 40;
    ws[OFF_XWT + j] = xproj_w[e * 256 + k];
  } else if (i < 73728 + 10240 + 128) {
    int co = i - 73728 - 10240;
    float inv = bn_g[co] * rsqrtf(bn_var[co] + 1e-5f);
    ws[OFF_BIAS2 + co] = (conv_b[co] - bn_mean[co]) * inv + bn_b[co];
  }
}

// =============== K1: conv3x3 s2 + BN + exact GELU (unchanged) ===============
__global__ __launch_bounds__(256) void k1_conv_bn_gelu(
    const float* __restrict__ x, const float* __restrict__ wt,
    const float* __restrict__ bias2, float* __restrict__ yds) {
  __shared__ float e_lds[16][3][66];
  __shared__ float o_lds[16][3][66];
  const int tid = threadIdx.x;
  const int ox = tid & 63;
  const int wv = __builtin_amdgcn_readfirstlane(tid >> 6);
  const int oy = blockIdx.x & 63, b = blockIdx.x >> 6;
  const int iy0 = 2 * oy - 1;
  float acc[32];
#pragma unroll
  for (int j = 0; j < 32; ++j) acc[j] = 0.f;

  for (int c = 0; c < 4; ++c) {
    const int ci0 = c * 16;
    __syncthreads();
    for (int idx = tid; idx < 16 * 3 * 32; idx += 256) {
      int cc = idx / 96; int rem = idx % 96; int r = rem >> 5; int xq = rem & 31;
      int iy = iy0 + r;
      float4 v = make_float4(0.f, 0.f, 0.f, 0.f);
      if (iy >= 0)
        v = *(const float4*)&x[(((size_t)(b * 64 + ci0 + cc) * 128) + iy) * 128 + xq * 4];
      e_lds[cc][r][2 * xq + 0] = v.x; e_lds[cc][r][2 * xq + 1] = v.z;
      o_lds[cc][r][2 * xq + 1] = v.y; o_lds[cc][r][2 * xq + 2] = v.w;
      if (xq == 0) o_lds[cc][r][0] = 0.f;
    }
    __syncthreads();
#pragma unroll 1
    for (int cc = 0; cc < 16; ++cc) {
#pragma unroll
      for (int kh = 0; kh < 3; ++kh) {
        float v0 = o_lds[cc][kh][ox];
        float v1 = e_lds[cc][kh][ox];
        float v2 = o_lds[cc][kh][ox + 1];
        const float* w0 = &wt[((ci0 + cc) * 9 + kh * 3 + 0) * 128 + wv * 32];
        const float* w1 = w0 + 128;
        const float* w2 = w0 + 256;
#pragma unroll
        for (int j = 0; j < 32; ++j) {
          acc[j] = fmaf(v0, w0[j], acc[j]);
          acc[j] = fmaf(v1, w1[j], acc[j]);
          acc[j] = fmaf(v2, w2[j], acc[j]);
        }
      }
    }
  }
  const int cobase = wv * 32;
#pragma unroll 4
  for (int j = 0; j < 32; ++j) {
    float v = acc[j] + bias2[cobase + j];
    float g = 0.5f * v * (1.f + erff(v * 0.70710678118f));
    yds[(((size_t)(b * 128 + cobase + j) * 64) + oy) * 64 + ox] = g;
  }
}

// =============== K2: in_proj GEMM -> t-major xpre[b][t][256], z[b][t][256] ===============
__global__ __launch_bounds__(256) void k2_inproj(
    const float* __restrict__ yds, const float* __restrict__ in_w,
    float* __restrict__ xpre, float* __restrict__ z) {
  __shared__ __align__(16) float a_lds[64][68];
  __shared__ __align__(16) float w_lds[64][68];
  const int tid = threadIdx.x;
  const int et = blockIdx.x & 7;
  const int rowid = blockIdx.x >> 3;
  const int oy = rowid & 63, b = rowid >> 6;
  const int t4 = (tid & 15) * 4, e4 = (tid >> 4) * 4;
  float acc[4][4];
#pragma unroll
  for (int i = 0; i < 4; ++i)
#pragma unroll
    for (int j = 0; j < 4; ++j) acc[i][j] = 0.f;

  for (int kc = 0; kc < 2; ++kc) {
    __syncthreads();
    for (int idx = tid; idx < 1024; idx += 256) {
      int k = idx >> 4, tq = idx & 15;
      *(float4*)&a_lds[k][tq * 4] =
          *(const float4*)&yds[(((size_t)(b * 128 + kc * 64 + k) * 64) + oy) * 64 + tq * 4];
    }
    for (int idx = tid; idx < 1024; idx += 256) {
      int j = idx >> 4, kq = idx & 15;
      float4 v = *(const float4*)&in_w[(size_t)(et * 64 + j) * 128 + kc * 64 + kq * 4];
      w_lds[kq * 4 + 0][j] = v.x; w_lds[kq * 4 + 1][j] = v.y;
      w_lds[kq * 4 + 2][j] = v.z; w_lds[kq * 4 + 3][j] = v.w;
    }
    __syncthreads();
#pragma unroll 8
    for (int k = 0; k < 64; ++k) {
      float4 a4 = *(const float4*)&a_lds[k][t4];
      float4 b4 = *(const float4*)&w_lds[k][e4];
      float av[4] = {a4.x, a4.y, a4.z, a4.w};
      float bv[4] = {b4.x, b4.y, b4.z, b4.w};
#pragma unroll
      for (int i = 0; i < 4; ++i)
#pragma unroll
        for (int j = 0; j < 4; ++j) acc[i][j] = fmaf(av[i], bv[j], acc[i][j]);
    }
  }
  const int e0 = et * 64 + e4;      // 0..511, float4 stays in one half
#pragma unroll
  for (int i = 0; i < 4; ++i) {
    int t = oy * 64 + t4 + i;
    float4 v = make_float4(acc[i][0], acc[i][1], acc[i][2], acc[i][3]);
    float* dst = (e0 < 256) ? (xpre + ((size_t)(b * 4096 + t)) * 256 + e0)
                            : (z + ((size_t)(b * 4096 + t)) * 256 + (e0 - 256));
    *(float4*)dst = v;
  }
}

// =============== K3: depthwise causal conv1d (k=4) + SiLU, t-major ===============
__global__ __launch_bounds__(256) void k3_conv1d_silu(
    const float* __restrict__ xpre, const float* __restrict__ w,
    const float* __restrict__ bvec, float* __restrict__ xin) {
  int i = blockIdx.x * 256 + threadIdx.x;  // over 4*4096*64
  int e4 = (i & 63) * 4;
  int t = (i >> 6) & 4095;
  int b = i >> 18;
  const float* base = xpre + (size_t)b * 4096 * 256;
  float4 zero = make_float4(0.f, 0.f, 0.f, 0.f);
  float4 r0 = (t >= 3) ? *(const float4*)&base[(size_t)(t - 3) * 256 + e4] : zero;
  float4 r1 = (t >= 2) ? *(const float4*)&base[(size_t)(t - 2) * 256 + e4] : zero;
  float4 r2 = (t >= 1) ? *(const float4*)&base[(size_t)(t - 1) * 256 + e4] : zero;
  float4 r3 = *(const float4*)&base[(size_t)t * 256 + e4];
  float4 w0 = *(const float4*)&w[(e4 + 0) * 4];
  float4 w1 = *(const float4*)&w[(e4 + 1) * 4];
  float4 w2 = *(const float4*)&w[(e4 + 2) * 4];
  float4 w3 = *(const float4*)&w[(e4 + 3) * 4];
  float4 bv = *(const float4*)&bvec[e4];
  float o0 = bv.x + w0.x * r0.x + w0.y * r1.x + w0.z * r2.x + w0.w * r3.x;
  float o1 = bv.y + w1.x * r0.y + w1.y * r1.y + w1.z * r2.y + w1.w * r3.y;
  float o2 = bv.z + w2.x * r0.z + w2.y * r1.z + w2.z * r2.z + w2.w * r3.z;
  float o3 = bv.w + w3.x * r0.w + w3.y * r1.w + w3.z * r2.w + w3.w * r3.w;
  *(float4*)&xin[((size_t)b * 4096 + t) * 256 + e4] =
      make_float4(fast_silu(o0), fast_silu(o1), fast_silu(o2), fast_silu(o3));
}

// =============== K4: x_proj + dt_proj + softplus; t-major in/out ===============
__global__ __launch_bounds__(256) void k4_xproj_delta(
    const float* __restrict__ xin, const float* __restrict__ xwt,
    const float* __restrict__ dtw, const float* __restrict__ dtb,
    float* __restrict__ delta, float* __restrict__ bc) {
  __shared__ float a_lds[128][65];     // [e][t] transposed
  __shared__ float xdbl[40][68];
  const int tid = threadIdx.x;
  const int t = tid & 63;
  const int wv = __builtin_amdgcn_readfirstlane(tid >> 6);
  const int tt = blockIdx.x & 63, b = blockIdx.x >> 6;
  const int t0 = tt * 64;
  float acc[10];
#pragma unroll
  for (int j = 0; j < 10; ++j) acc[j] = 0.f;

  for (int kh2 = 0; kh2 < 2; ++kh2) {
    __syncthreads();
    for (int idx = tid; idx < 2048; idx += 256) {
      int tl = idx >> 5; int e4 = (idx & 31) * 4;
      float4 v = *(const float4*)&xin[((size_t)(b * 4096 + t0 + tl)) * 256 + kh2 * 128 + e4];
      a_lds[e4 + 0][tl] = v.x; a_lds[e4 + 1][tl] = v.y;
      a_lds[e4 + 2][tl] = v.z; a_lds[e4 + 3][tl] = v.w;
    }
    __syncthreads();
#pragma unroll 4
    for (int k = 0; k < 128; ++k) {
      float av = a_lds[k][t];
      const float* wrow = &xwt[(kh2 * 128 + k) * 40 + wv * 10];
#pragma unroll
      for (int j = 0; j < 10; ++j) acc[j] = fmaf(av, wrow[j], acc[j]);
    }
  }
#pragma unroll
  for (int j = 0; j < 10; ++j) xdbl[wv * 10 + j][t] = acc[j];
  __syncthreads();

  // delta: thread per d; stores coalesced per t (lanes = d)
  {
    int d = tid;
    float4 wa = *(const float4*)&dtw[d * 8];
    float4 wb = *(const float4*)&dtw[d * 8 + 4];
    float bias = dtb[d];
    float* dst = delta + ((size_t)(b * 4096 + t0)) * 256 + d;
#pragma unroll 4
    for (int tl = 0; tl < 64; ++tl) {
      float s = bias;
      s = fmaf(wa.x, xdbl[0][tl], s); s = fmaf(wa.y, xdbl[1][tl], s);
      s = fmaf(wa.z, xdbl[2][tl], s); s = fmaf(wa.w, xdbl[3][tl], s);
      s = fmaf(wb.x, xdbl[4][tl], s); s = fmaf(wb.y, xdbl[5][tl], s);
      s = fmaf(wb.z, xdbl[6][tl], s); s = fmaf(wb.w, xdbl[7][tl], s);
      dst[(size_t)tl * 256] = fmaxf(s, 0.f) + log1pf(__expf(-fabsf(s)));
    }
  }
  // B/C -> bc[b][t][32]
  for (int idx = tid; idx < 2048; idx += 256) {
    int tl = idx >> 5, m = idx & 31;
    bc[((size_t)(b * 4096 + t0 + tl)) * 32 + m] = xdbl[8 + m][tl];
  }
}

// =============== scan helpers ===============
template <int CTRL>
DEV float dpp_add(float v) {
  int s = __builtin_amdgcn_update_dpp(0, __float_as_int(v), CTRL, 0xF, 0xF, true);
  return v + __int_as_float(s);
}

// thread map for scan passes: q = tid&3 (4 n-states), dloc = tid>>2 (64 d/block)
// grid: bx -> chunk (32), dblk (4), b (4) = 512 blocks
// =============== K5a: pass 1 -> S (chunk-local scan) + dsum (for P) ===============
__global__ __launch_bounds__(256) void k5a_scan1(
    const float* __restrict__ delta, const float* __restrict__ xin,
    const float* __restrict__ bc, const float* __restrict__ A_log,
    float* __restrict__ S, float* __restrict__ dsum) {
  const int tid = threadIdx.x;
  const int q = tid & 3, dloc = tid >> 2;
  const int bx = blockIdx.x;
  const int chunk = bx & 31, dblk = (bx >> 5) & 3, b = bx >> 7;
  const int d = dblk * 64 + dloc;
  const int t0 = chunk * TCH;
  float4 al = *(const float4*)&A_log[d * 16 + q * 4];
  float A2[4] = {-__expf(al.x) * L2E, -__expf(al.y) * L2E,
                 -__expf(al.z) * L2E, -__expf(al.w) * L2E};
  float h[4] = {0.f, 0.f, 0.f, 0.f};
  float ds = 0.f;
  const float* pd = delta + ((size_t)(b * 4096 + t0)) * 256 + d;
  const float* px = xin + ((size_t)(b * 4096 + t0)) * 256 + d;
  const float* pb = bc + ((size_t)(b * 4096 + t0)) * 32 + q * 4;
#pragma unroll 4
  for (int i = 0; i < TCH; ++i) {
    float dl = pd[(size_t)i * 256];
    float xv = px[(size_t)i * 256];
    float4 B4 = *(const float4*)&pb[(size_t)i * 32];
    float dlx = dl * xv;
    ds += dl;
    h[0] = fmaf(exp2f(dl * A2[0]), h[0], dlx * B4.x);
    h[1] = fmaf(exp2f(dl * A2[1]), h[1], dlx * B4.y);
    h[2] = fmaf(exp2f(dl * A2[2]), h[2], dlx * B4.z);
    h[3] = fmaf(exp2f(dl * A2[3]), h[3], dlx * B4.w);
  }
  int rowd = (b * 32 + chunk) * 256 + d;
  *(float4*)&S[(size_t)rowd * 16 + q * 4] = make_float4(h[0], h[1], h[2], h[3]);
  if (q == 0) dsum[rowd] = ds;
}

// =============== K5b: combine chunk boundaries; hinit written in-place over S ===============
__global__ __launch_bounds__(256) void k5b_combine(
    float* __restrict__ S /* in: chunk scans; out: hinit */,
    const float* __restrict__ dsum, const float* __restrict__ A_log) {
  int g = blockIdx.x * 256 + threadIdx.x;    // 16384 threads
  int n = g & 15, d = (g >> 4) & 255, b = g >> 12;
  float A2 = -__expf(A_log[d * 16 + n]) * L2E;
  float h = 0.f;
#pragma unroll 1
  for (int c = 0; c < NCH; ++c) {
    int rowd = (b * 32 + c) * 256 + d;
    size_t idx = (size_t)rowd * 16 + n;
    float s = S[idx];
    float P = exp2f(A2 * dsum[rowd]);
    S[idx] = h;                 // hinit (s already read)
    h = fmaf(P, h, s);
  }
}

// =============== K5c: pass 2 -> y, fused (+x*Dp)*silu(z), t-major store ===============
__global__ __launch_bounds__(256) void k5c_scan2(
    const float* __restrict__ delta, const float* __restrict__ xin,
    const float* __restrict__ bc, const float* __restrict__ z,
    const float* __restrict__ A_log, const float* __restrict__ Dp,
    const float* __restrict__ hinit, float* __restrict__ yact) {
  const int tid = threadIdx.x;
  const int q = tid & 3, dloc = tid >> 2;
  const int bx = blockIdx.x;
  const int chunk = bx & 31, dblk = (bx >> 5) & 3, b = bx >> 7;
  const int d = dblk * 64 + dloc;
  const int t0 = chunk * TCH;
  float4 al = *(const float4*)&A_log[d * 16 + q * 4];
  float A2[4] = {-__expf(al.x) * L2E, -__expf(al.y) * L2E,
                 -__expf(al.z) * L2E, -__expf(al.w) * L2E};
  const float Dpd = Dp[d];
  int rowd = (b * 32 + chunk) * 256 + d;
  float4 hv = *(const float4*)&hinit[(size_t)rowd * 16 + q * 4];
  float h[4] = {hv.x, hv.y, hv.z, hv.w};
  const float* pd = delta + ((size_t)(b * 4096 + t0)) * 256 + d;
  const float* px = xin + ((size_t)(b * 4096 + t0)) * 256 + d;
  const float* pz = z + ((size_t)(b * 4096 + t0)) * 256 + d;
  const float* pb = bc + ((size_t)(b * 4096 + t0)) * 32 + q * 4;
  const float* pc = pb + 16;
  float* py = yact + ((size_t)(b * 4096 + t0)) * 256 + d;
#pragma unroll 4
  for (int i = 0; i < TCH; ++i) {
    float dl = pd[(size_t)i * 256];
    float xv = px[(size_t)i * 256];
    float zv = pz[(size_t)i * 256];
    float4 B4 = *(const float4*)&pb[(size_t)i * 32];
    float4 C4 = *(const float4*)&pc[(size_t)i * 32];
    float dlx = dl * xv;
    h[0] = fmaf(exp2f(dl * A2[0]), h[0], dlx * B4.x);
    h[1] = fmaf(exp2f(dl * A2[1]), h[1], dlx * B4.y);
    h[2] = fmaf(exp2f(dl * A2[2]), h[2], dlx * B4.z);
    h[3] = fmaf(exp2f(dl * A2[3]), h[3], dlx * B4.w);
    float y = h[0] * C4.x;
    y = fmaf(h[1], C4.y, y);
    y = fmaf(h[2], C4.z, y);
    y = fmaf(h[3], C4.w, y);
    y = dpp_add<0xB1>(y);     // quad_perm [1,0,3,2]
    y = dpp_add<0x4E>(y);     // quad_perm [2,3,0,1] -> sum over 4 q-lanes
    float out = (y + xv * Dpd) * fast_silu(zv);
    if (q == 0) py[(size_t)i * 256] = out;
  }
}

// =============== K6: out_proj GEMM + residual (reads t-major yact) ===============
__global__ __launch_bounds__(256) void k6_outproj(
    const float* __restrict__ yact, const float* __restrict__ out_w,
    const float* __restrict__ yds, float* __restrict__ out) {
  __shared__ __align__(16) float a_lds[64][68];   // [e][t] transposed
  __shared__ __align__(16) float w_lds[64][132];
  const int tid = threadIdx.x;
  const int oy = blockIdx.x & 63, b = blockIdx.x >> 6;
  const int t4 = (tid & 15) * 4, c8 = (tid >> 4) * 8;
  float acc[4][8];
#pragma unroll
  for (int i = 0; i < 4; ++i)
#pragma unroll
    for (int j = 0; j < 8; ++j) acc[i][j] = 0.f;

  for (int kc = 0; kc < 4; ++kc) {
    __syncthreads();
    for (int idx = tid; idx < 1024; idx += 256) {
      int tl = idx >> 4; int e4 = (idx & 15) * 4;
      float4 v = *(const float4*)&yact[((size_t)(b * 4096 + oy * 64 + tl)) * 256 + kc * 64 + e4];
      a_lds[e4 + 0][tl] = v.x; a_lds[e4 + 1][tl] = v.y;
      a_lds[e4 + 2][tl] = v.z; a_lds[e4 + 3][tl] = v.w;
    }
    for (int idx = tid; idx < 2048; idx += 256) {
      int cc = idx >> 4, kq = idx & 15;
      float4 v = *(const float4*)&out_w[(size_t)cc * 256 + kc * 64 + kq * 4];
      w_lds[kq * 4 + 0][cc] = v.x; w_lds[kq * 4 + 1][cc] = v.y;
      w_lds[kq * 4 + 2][cc] = v.z; w_lds[kq * 4 + 3][cc] = v.w;
    }
    __syncthreads();
#pragma unroll 4
    for (int k = 0; k < 64; ++k) {
      float4 a4 = *(const float4*)&a_lds[k][t4];
      float4 b0 = *(const float4*)&w_lds[k][c8];
      float4 b1 = *(const float4*)&w_lds[k][c8 + 4];
      float av[4] = {a4.x, a4.y, a4.z, a4.w};
      float bv[8] = {b0.x, b0.y, b0.z, b0.w, b1.x, b1.y, b1.z, b1.w};
#pragma unroll
      for (int i = 0; i < 4; ++i)
#pragma unroll
        for (int j = 0; j < 8; ++j) acc[i][j] = fmaf(av[i], bv[j], acc[i][j]);
    }
  }
#pragma unroll
  for (int j = 0; j < 8; ++j) {
    int cc = c8 + j;
    size_t base = (((size_t)(b * 128 + cc) * 64) + oy) * 64 + t4;
    float4 r = *(const float4*)&yds[base];
    *(float4*)&out[base] = make_float4(acc[0][j] + r.x, acc[1][j] + r.y,
                                       acc[2][j] + r.z, acc[3][j] + r.w);
  }
}

// =============== launch ===============
extern "C" void kernel_launch(void* const* d_in, const int* in_sizes, int n_in,
                              void* d_out, int out_size, void* d_ws, size_t ws_size,
                              hipStream_t stream) {
  (void)in_sizes; (void)n_in; (void)out_size; (void)ws_size;
  const float* x        = (const float*)d_in[0];
  const float* conv_w   = (const float*)d_in[1];
  const float* conv_b   = (const float*)d_in[2];
  const float* bn_g     = (const float*)d_in[3];
  const float* bn_b     = (const float*)d_in[4];
  const float* bn_mean  = (const float*)d_in[5];
  const float* bn_var   = (const float*)d_in[6];
  const float* in_w     = (const float*)d_in[7];
  const float* conv1d_w = (const float*)d_in[8];
  const float* conv1d_b = (const float*)d_in[9];
  const float* xproj_w  = (const float*)d_in[10];
  const float* dtproj_w = (const float*)d_in[11];
  const float* dtproj_b = (const float*)d_in[12];
  const float* A_log    = (const float*)d_in[13];
  const float* Dp       = (const float*)d_in[14];
  const float* out_w    = (const float*)d_in[15];
  float* ws = (float*)d_ws;
  float* out = (float*)d_out;

  k0_prep<<<329, 256, 0, stream>>>(conv_w, conv_b, bn_g, bn_b, bn_mean, bn_var,
                                   xproj_w, ws);
  k1_conv_bn_gelu<<<256, 256, 0, stream>>>(x, ws + OFF_WT, ws + OFF_BIAS2,
                                           ws + OFF_YDS);
  k2_inproj<<<2048, 256, 0, stream>>>(ws + OFF_YDS, in_w, ws + OFF_XPRE, ws + OFF_Z);
  k3_conv1d_silu<<<4096, 256, 0, stream>>>(ws + OFF_XPRE, conv1d_w, conv1d_b,
                                           ws + OFF_XIN);
  k4_xproj_delta<<<256, 256, 0, stream>>>(ws + OFF_XIN, ws + OFF_XWT, dtproj_w,
                                          dtproj_b, ws + OFF_DELTA, ws + OFF_BC);
  k5a_scan1<<<512, 256, 0, stream>>>(ws + OFF_DELTA, ws + OFF_XIN, ws + OFF_BC,
                                     A_log, ws + OFF_S, ws + OFF_DSUM);
  k5b_combine<<<64, 256, 0, stream>>>(ws + OFF_S, ws + OFF_DSUM, A_log);
  k5c_scan2<<<512, 256, 0, stream>>>(ws + OFF_DELTA, ws + OFF_XIN, ws + OFF_BC,
                                     ws + OFF_Z, A_log, Dp, ws + OFF_S,
                                     ws + OFF_YACT);
  k6_outproj<<<256, 256, 0, stream>>>(ws + OFF_YACT, out_w, ws + OFF_YDS, out);
}

// Round 3
// 392.819 us; speedup vs baseline: 1.6043x; 1.1920x over previous
//
#include <hip/hip_runtime.h>
#include <math.h>

// ---------------- problem sizes ----------------
#define NB 4
#define LTOK 4096
#define DM 128
#define DI 256
#define NCH 32     // scan chunks
#define TCH 128    // steps per chunk

// ---------------- workspace layout (float offsets) ----------------
// all mamba intermediates are t-major: [b][t][e]
#define OFF_WT     0u          // [64ci][9tap][128co] conv weights * bn_inv (73728)
#define OFF_BIAS2  73728u      // folded conv+bn bias [128]
#define OFF_XWT    73856u      // xproj_w transposed [256k][40e] (10240)
#define OFF_YDS    84096u      // gelu output [4][128][64][64]  (2097152)
#define OFF_XPRE   2181248u    // [4][4096][256]
#define OFF_Z      6375552u    // [4][4096][256]
#define OFF_XIN    10569856u   // [4][4096][256]
#define OFF_DELTA  14764160u   // [4][4096][256]
#define OFF_BC     18958464u   // [4][4096][32]  cols 0-15 B, 16-31 C (524288)
#define OFF_S      19482752u   // [4][32c][256d][16n] (524288); reused as hinit
#define OFF_DSUM   20007040u   // [4][32c][256d] (32768)
#define OFF_YACT   OFF_XPRE    // xpre dead after conv1d; reuse
// total 20039808 floats = 80.2 MB

#define DEV __device__ __forceinline__
#define L2E 1.4426950408889634f

DEV float fast_silu(float v) {
  return v * __builtin_amdgcn_rcpf(1.f + __expf(-v));
}

// =============== K0: fold BN into conv weights; transpose xproj_w ===============
__global__ __launch_bounds__(256) void k0_prep(
    const float* __restrict__ conv_w, const float* __restrict__ conv_b,
    const float* __restrict__ bn_g, const float* __restrict__ bn_b,
    const float* __restrict__ bn_mean, const float* __restrict__ bn_var,
    const float* __restrict__ xproj_w, float* __restrict__ ws) {
  int i = blockIdx.x * 256 + threadIdx.x;
  if (i < 73728) {
    int co = i & 127; int tap = (i >> 7) % 9; int ci = i / 1152;
    float inv = bn_g[co] * rsqrtf(bn_var[co] + 1e-5f);
    ws[OFF_WT + i] = conv_w[co * 576 + ci * 9 + tap] * inv;
  } else if (i < 73728 + 10240) {
    int j = i - 73728; int e = j % 40; int k = j / 40;
    ws[OFF_XWT + j] = xproj_w[e * 256 + k];
  } else if (i < 73728 + 10240 + 128) {
    int co = i - 73728 - 10240;
    float inv = bn_g[co] * rsqrtf(bn_var[co] + 1e-5f);
    ws[OFF_BIAS2 + co] = (conv_b[co] - bn_mean[co]) * inv + bn_b[co];
  }
}

// =============== K1: conv3x3 s2 + BN + exact GELU ===============
// grid 1024 = (b=4, oy=64, cog=4). Block: 4 waves x 64 ox lanes; wave wv does
// 8 c_out (cobase = cog*32 + wv*8). 4 blocks/CU -> 4 waves/SIMD for latency hiding.
__global__ __launch_bounds__(256) void k1_conv_bn_gelu(
    const float* __restrict__ x, const float* __restrict__ wt,
    const float* __restrict__ bias2, float* __restrict__ yds) {
  __shared__ float e_lds[16][3][66];
  __shared__ float o_lds[16][3][66];
  const int tid = threadIdx.x;
  const int ox = tid & 63;
  const int wv = __builtin_amdgcn_readfirstlane(tid >> 6);
  const int cog = blockIdx.x & 3;
  const int oy = (blockIdx.x >> 2) & 63;
  const int b = blockIdx.x >> 8;
  const int iy0 = 2 * oy - 1;
  const int cobase = cog * 32 + wv * 8;
  float acc[8];
#pragma unroll
  for (int j = 0; j < 8; ++j) acc[j] = 0.f;

  for (int c = 0; c < 4; ++c) {
    const int ci0 = c * 16;
    __syncthreads();
    for (int idx = tid; idx < 16 * 3 * 32; idx += 256) {
      int cc = idx / 96; int rem = idx % 96; int r = rem >> 5; int xq = rem & 31;
      int iy = iy0 + r;
      float4 v = make_float4(0.f, 0.f, 0.f, 0.f);
      if (iy >= 0)
        v = *(const float4*)&x[(((size_t)(b * 64 + ci0 + cc) * 128) + iy) * 128 + xq * 4];
      e_lds[cc][r][2 * xq + 0] = v.x; e_lds[cc][r][2 * xq + 1] = v.z;
      o_lds[cc][r][2 * xq + 1] = v.y; o_lds[cc][r][2 * xq + 2] = v.w;
      if (xq == 0) o_lds[cc][r][0] = 0.f;
    }
    __syncthreads();
#pragma unroll 1
    for (int cc = 0; cc < 16; ++cc) {
#pragma unroll
      for (int kh = 0; kh < 3; ++kh) {
        float v0 = o_lds[cc][kh][ox];       // kw=0 -> x[2ox-1]
        float v1 = e_lds[cc][kh][ox];       // kw=1 -> x[2ox]
        float v2 = o_lds[cc][kh][ox + 1];   // kw=2 -> x[2ox+1]
        const float* w0 = &wt[((ci0 + cc) * 9 + kh * 3 + 0) * 128 + cobase];
        const float* w1 = w0 + 128;
        const float* w2 = w0 + 256;
#pragma unroll
        for (int j = 0; j < 8; ++j) {
          acc[j] = fmaf(v0, w0[j], acc[j]);
          acc[j] = fmaf(v1, w1[j], acc[j]);
          acc[j] = fmaf(v2, w2[j], acc[j]);
        }
      }
    }
  }
#pragma unroll
  for (int j = 0; j < 8; ++j) {
    float v = acc[j] + bias2[cobase + j];
    float g = 0.5f * v * (1.f + erff(v * 0.70710678118f));
    yds[(((size_t)(b * 128 + cobase + j) * 64) + oy) * 64 + ox] = g;
  }
}

// =============== K2: in_proj GEMM -> t-major xpre[b][t][256], z[b][t][256] ===============
__global__ __launch_bounds__(256) void k2_inproj(
    const float* __restrict__ yds, const float* __restrict__ in_w,
    float* __restrict__ xpre, float* __restrict__ z) {
  __shared__ __align__(16) float a_lds[64][68];
  __shared__ __align__(16) float w_lds[64][68];
  const int tid = threadIdx.x;
  const int et = blockIdx.x & 7;
  const int rowid = blockIdx.x >> 3;
  const int oy = rowid & 63, b = rowid >> 6;
  const int t4 = (tid & 15) * 4, e4 = (tid >> 4) * 4;
  float acc[4][4];
#pragma unroll
  for (int i = 0; i < 4; ++i)
#pragma unroll
    for (int j = 0; j < 4; ++j) acc[i][j] = 0.f;

  for (int kc = 0; kc < 2; ++kc) {
    __syncthreads();
    for (int idx = tid; idx < 1024; idx += 256) {
      int k = idx >> 4, tq = idx & 15;
      *(float4*)&a_lds[k][tq * 4] =
          *(const float4*)&yds[(((size_t)(b * 128 + kc * 64 + k) * 64) + oy) * 64 + tq * 4];
    }
    for (int idx = tid; idx < 1024; idx += 256) {
      int j = idx >> 4, kq = idx & 15;
      float4 v = *(const float4*)&in_w[(size_t)(et * 64 + j) * 128 + kc * 64 + kq * 4];
      w_lds[kq * 4 + 0][j] = v.x; w_lds[kq * 4 + 1][j] = v.y;
      w_lds[kq * 4 + 2][j] = v.z; w_lds[kq * 4 + 3][j] = v.w;
    }
    __syncthreads();
#pragma unroll 8
    for (int k = 0; k < 64; ++k) {
      float4 a4 = *(const float4*)&a_lds[k][t4];
      float4 b4 = *(const float4*)&w_lds[k][e4];
      float av[4] = {a4.x, a4.y, a4.z, a4.w};
      float bv[4] = {b4.x, b4.y, b4.z, b4.w};
#pragma unroll
      for (int i = 0; i < 4; ++i)
#pragma unroll
        for (int j = 0; j < 4; ++j) acc[i][j] = fmaf(av[i], bv[j], acc[i][j]);
    }
  }
  const int e0 = et * 64 + e4;      // 0..511, float4 stays in one half
#pragma unroll
  for (int i = 0; i < 4; ++i) {
    int t = oy * 64 + t4 + i;
    float4 v = make_float4(acc[i][0], acc[i][1], acc[i][2], acc[i][3]);
    float* dst = (e0 < 256) ? (xpre + ((size_t)(b * 4096 + t)) * 256 + e0)
                            : (z + ((size_t)(b * 4096 + t)) * 256 + (e0 - 256));
    *(float4*)dst = v;
  }
}

// =============== K3: depthwise causal conv1d (k=4) + SiLU, t-major ===============
__global__ __launch_bounds__(256) void k3_conv1d_silu(
    const float* __restrict__ xpre, const float* __restrict__ w,
    const float* __restrict__ bvec, float* __restrict__ xin) {
  int i = blockIdx.x * 256 + threadIdx.x;  // over 4*4096*64
  int e4 = (i & 63) * 4;
  int t = (i >> 6) & 4095;
  int b = i >> 18;
  const float* base = xpre + (size_t)b * 4096 * 256;
  float4 zero = make_float4(0.f, 0.f, 0.f, 0.f);
  float4 r0 = (t >= 3) ? *(const float4*)&base[(size_t)(t - 3) * 256 + e4] : zero;
  float4 r1 = (t >= 2) ? *(const float4*)&base[(size_t)(t - 2) * 256 + e4] : zero;
  float4 r2 = (t >= 1) ? *(const float4*)&base[(size_t)(t - 1) * 256 + e4] : zero;
  float4 r3 = *(const float4*)&base[(size_t)t * 256 + e4];
  float4 w0 = *(const float4*)&w[(e4 + 0) * 4];
  float4 w1 = *(const float4*)&w[(e4 + 1) * 4];
  float4 w2 = *(const float4*)&w[(e4 + 2) * 4];
  float4 w3 = *(const float4*)&w[(e4 + 3) * 4];
  float4 bv = *(const float4*)&bvec[e4];
  float o0 = bv.x + w0.x * r0.x + w0.y * r1.x + w0.z * r2.x + w0.w * r3.x;
  float o1 = bv.y + w1.x * r0.y + w1.y * r1.y + w1.z * r2.y + w1.w * r3.y;
  float o2 = bv.z + w2.x * r0.z + w2.y * r1.z + w2.z * r2.z + w2.w * r3.z;
  float o3 = bv.w + w3.x * r0.w + w3.y * r1.w + w3.z * r2.w + w3.w * r3.w;
  *(float4*)&xin[((size_t)b * 4096 + t) * 256 + e4] =
      make_float4(fast_silu(o0), fast_silu(o1), fast_silu(o2), fast_silu(o3));
}

// =============== K4: x_proj + dt_proj + softplus; t-major in/out ===============
__global__ __launch_bounds__(256) void k4_xproj_delta(
    const float* __restrict__ xin, const float* __restrict__ xwt,
    const float* __restrict__ dtw, const float* __restrict__ dtb,
    float* __restrict__ delta, float* __restrict__ bc) {
  __shared__ float a_lds[128][65];     // [e][t] transposed
  __shared__ float xdbl[40][68];
  const int tid = threadIdx.x;
  const int t = tid & 63;
  const int wv = __builtin_amdgcn_readfirstlane(tid >> 6);
  const int tt = blockIdx.x & 63, b = blockIdx.x >> 6;
  const int t0 = tt * 64;
  float acc[10];
#pragma unroll
  for (int j = 0; j < 10; ++j) acc[j] = 0.f;

  for (int kh2 = 0; kh2 < 2; ++kh2) {
    __syncthreads();
    for (int idx = tid; idx < 2048; idx += 256) {
      int tl = idx >> 5; int e4 = (idx & 31) * 4;
      float4 v = *(const float4*)&xin[((size_t)(b * 4096 + t0 + tl)) * 256 + kh2 * 128 + e4];
      a_lds[e4 + 0][tl] = v.x; a_lds[e4 + 1][tl] = v.y;
      a_lds[e4 + 2][tl] = v.z; a_lds[e4 + 3][tl] = v.w;
    }
    __syncthreads();
#pragma unroll 4
    for (int k = 0; k < 128; ++k) {
      float av = a_lds[k][t];
      const float* wrow = &xwt[(kh2 * 128 + k) * 40 + wv * 10];
#pragma unroll
      for (int j = 0; j < 10; ++j) acc[j] = fmaf(av, wrow[j], acc[j]);
    }
  }
#pragma unroll
  for (int j = 0; j < 10; ++j) xdbl[wv * 10 + j][t] = acc[j];
  __syncthreads();

  // delta: thread per d; stores coalesced per t (lanes = d)
  {
    int d = tid;
    float4 wa = *(const float4*)&dtw[d * 8];
    float4 wb = *(const float4*)&dtw[d * 8 + 4];
    float bias = dtb[d];
    float* dst = delta + ((size_t)(b * 4096 + t0)) * 256 + d;
#pragma unroll 4
    for (int tl = 0; tl < 64; ++tl) {
      float s = bias;
      s = fmaf(wa.x, xdbl[0][tl], s); s = fmaf(wa.y, xdbl[1][tl], s);
      s = fmaf(wa.z, xdbl[2][tl], s); s = fmaf(wa.w, xdbl[3][tl], s);
      s = fmaf(wb.x, xdbl[4][tl], s); s = fmaf(wb.y, xdbl[5][tl], s);
      s = fmaf(wb.z, xdbl[6][tl], s); s = fmaf(wb.w, xdbl[7][tl], s);
      dst[(size_t)tl * 256] = fmaxf(s, 0.f) + log1pf(__expf(-fabsf(s)));
    }
  }
  // B/C -> bc[b][t][32]
  for (int idx = tid; idx < 2048; idx += 256) {
    int tl = idx >> 5, m = idx & 31;
    bc[((size_t)(b * 4096 + t0 + tl)) * 32 + m] = xdbl[8 + m][tl];
  }
}

// =============== scan helpers ===============
template <int CTRL>
DEV float dpp_add(float v) {
  int s = __builtin_amdgcn_update_dpp(0, __float_as_int(v), CTRL, 0xF, 0xF, true);
  return v + __int_as_float(s);
}

// thread map for scan passes: q = tid&3 (4 n-states), dloc = tid>>2 (64 d/block)
// grid: bx -> chunk (32), dblk (4), b (4) = 512 blocks
// =============== K5a: pass 1 -> S (chunk-local scan) + dsum (for P) ===============
__global__ __launch_bounds__(256) void k5a_scan1(
    const float* __restrict__ delta, const float* __restrict__ xin,
    const float* __restrict__ bc, const float* __restrict__ A_log,
    float* __restrict__ S, float* __restrict__ dsum) {
  const int tid = threadIdx.x;
  const int q = tid & 3, dloc = tid >> 2;
  const int bx = blockIdx.x;
  const int chunk = bx & 31, dblk = (bx >> 5) & 3, b = bx >> 7;
  const int d = dblk * 64 + dloc;
  const int t0 = chunk * TCH;
  float4 al = *(const float4*)&A_log[d * 16 + q * 4];
  float A2[4] = {-__expf(al.x) * L2E, -__expf(al.y) * L2E,
                 -__expf(al.z) * L2E, -__expf(al.w) * L2E};
  float h[4] = {0.f, 0.f, 0.f, 0.f};
  float ds = 0.f;
  const float* pd = delta + ((size_t)(b * 4096 + t0)) * 256 + d;
  const float* px = xin + ((size_t)(b * 4096 + t0)) * 256 + d;
  const float* pb = bc + ((size_t)(b * 4096 + t0)) * 32 + q * 4;
#pragma unroll 4
  for (int i = 0; i < TCH; ++i) {
    float dl = pd[(size_t)i * 256];
    float xv = px[(size_t)i * 256];
    float4 B4 = *(const float4*)&pb[(size_t)i * 32];
    float dlx = dl * xv;
    ds += dl;
    h[0] = fmaf(exp2f(dl * A2[0]), h[0], dlx * B4.x);
    h[1] = fmaf(exp2f(dl * A2[1]), h[1], dlx * B4.y);
    h[2] = fmaf(exp2f(dl * A2[2]), h[2], dlx * B4.z);
    h[3] = fmaf(exp2f(dl * A2[3]), h[3], dlx * B4.w);
  }
  int rowd = (b * 32 + chunk) * 256 + d;
  *(float4*)&S[(size_t)rowd * 16 + q * 4] = make_float4(h[0], h[1], h[2], h[3]);
  if (q == 0) dsum[rowd] = ds;
}

// =============== K5b: combine chunk boundaries; hinit written in-place over S ===============
__global__ __launch_bounds__(256) void k5b_combine(
    float* __restrict__ S /* in: chunk scans; out: hinit */,
    const float* __restrict__ dsum, const float* __restrict__ A_log) {
  int g = blockIdx.x * 256 + threadIdx.x;    // 16384 threads
  int n = g & 15, d = (g >> 4) & 255, b = g >> 12;
  float A2 = -__expf(A_log[d * 16 + n]) * L2E;
  float h = 0.f;
#pragma unroll 1
  for (int c = 0; c < NCH; ++c) {
    int rowd = (b * 32 + c) * 256 + d;
    size_t idx = (size_t)rowd * 16 + n;
    float s = S[idx];
    float P = exp2f(A2 * dsum[rowd]);
    S[idx] = h;                 // hinit (s already read)
    h = fmaf(P, h, s);
  }
}

// =============== K5c: pass 2 -> y, fused (+x*Dp)*silu(z), t-major store ===============
__global__ __launch_bounds__(256) void k5c_scan2(
    const float* __restrict__ delta, const float* __restrict__ xin,
    const float* __restrict__ bc, const float* __restrict__ z,
    const float* __restrict__ A_log, const float* __restrict__ Dp,
    const float* __restrict__ hinit, float* __restrict__ yact) {
  const int tid = threadIdx.x;
  const int q = tid & 3, dloc = tid >> 2;
  const int bx = blockIdx.x;
  const int chunk = bx & 31, dblk = (bx >> 5) & 3, b = bx >> 7;
  const int d = dblk * 64 + dloc;
  const int t0 = chunk * TCH;
  float4 al = *(const float4*)&A_log[d * 16 + q * 4];
  float A2[4] = {-__expf(al.x) * L2E, -__expf(al.y) * L2E,
                 -__expf(al.z) * L2E, -__expf(al.w) * L2E};
  const float Dpd = Dp[d];
  int rowd = (b * 32 + chunk) * 256 + d;
  float4 hv = *(const float4*)&hinit[(size_t)rowd * 16 + q * 4];
  float h[4] = {hv.x, hv.y, hv.z, hv.w};
  const float* pd = delta + ((size_t)(b * 4096 + t0)) * 256 + d;
  const float* px = xin + ((size_t)(b * 4096 + t0)) * 256 + d;
  const float* pz = z + ((size_t)(b * 4096 + t0)) * 256 + d;
  const float* pb = bc + ((size_t)(b * 4096 + t0)) * 32 + q * 4;
  const float* pc = pb + 16;
  float* py = yact + ((size_t)(b * 4096 + t0)) * 256 + d;
#pragma unroll 4
  for (int i = 0; i < TCH; ++i) {
    float dl = pd[(size_t)i * 256];
    float xv = px[(size_t)i * 256];
    float zv = pz[(size_t)i * 256];
    float4 B4 = *(const float4*)&pb[(size_t)i * 32];
    float4 C4 = *(const float4*)&pc[(size_t)i * 32];
    float dlx = dl * xv;
    h[0] = fmaf(exp2f(dl * A2[0]), h[0], dlx * B4.x);
    h[1] = fmaf(exp2f(dl * A2[1]), h[1], dlx * B4.y);
    h[2] = fmaf(exp2f(dl * A2[2]), h[2], dlx * B4.z);
    h[3] = fmaf(exp2f(dl * A2[3]), h[3], dlx * B4.w);
    float y = h[0] * C4.x;
    y = fmaf(h[1], C4.y, y);
    y = fmaf(h[2], C4.z, y);
    y = fmaf(h[3], C4.w, y);
    y = dpp_add<0xB1>(y);     // quad_perm [1,0,3,2]
    y = dpp_add<0x4E>(y);     // quad_perm [2,3,0,1] -> sum over 4 q-lanes
    float out = (y + xv * Dpd) * fast_silu(zv);
    if (q == 0) py[(size_t)i * 256] = out;
  }
}

// =============== K6: out_proj GEMM + residual (reads t-major yact) ===============
__global__ __launch_bounds__(256) void k6_outproj(
    const float* __restrict__ yact, const float* __restrict__ out_w,
    const float* __restrict__ yds, float* __restrict__ out) {
  __shared__ __align__(16) float a_lds[64][68];   // [e][t] transposed
  __shared__ __align__(16) float w_lds[64][132];
  const int tid = threadIdx.x;
  const int oy = blockIdx.x & 63, b = blockIdx.x >> 6;
  const int t4 = (tid & 15) * 4, c8 = (tid >> 4) * 8;
  float acc[4][8];
#pragma unroll
  for (int i = 0; i < 4; ++i)
#pragma unroll
    for (int j = 0; j < 8; ++j) acc[i][j] = 0.f;

  for (int kc = 0; kc < 4; ++kc) {
    __syncthreads();
    for (int idx = tid; idx < 1024; idx += 256) {
      int tl = idx >> 4; int e4 = (idx & 15) * 4;
      float4 v = *(const float4*)&yact[((size_t)(b * 4096 + oy * 64 + tl)) * 256 + kc * 64 + e4];
      a_lds[e4 + 0][tl] = v.x; a_lds[e4 + 1][tl] = v.y;
      a_lds[e4 + 2][tl] = v.z; a_lds[e4 + 3][tl] = v.w;
    }
    for (int idx = tid; idx < 2048; idx += 256) {
      int cc = idx >> 4, kq = idx & 15;
      float4 v = *(const float4*)&out_w[(size_t)cc * 256 + kc * 64 + kq * 4];
      w_lds[kq * 4 + 0][cc] = v.x; w_lds[kq * 4 + 1][cc] = v.y;
      w_lds[kq * 4 + 2][cc] = v.z; w_lds[kq * 4 + 3][cc] = v.w;
    }
    __syncthreads();
#pragma unroll 4
    for (int k = 0; k < 64; ++k) {
      float4 a4 = *(const float4*)&a_lds[k][t4];
      float4 b0 = *(const float4*)&w_lds[k][c8];
      float4 b1 = *(const float4*)&w_lds[k][c8 + 4];
      float av[4] = {a4.x, a4.y, a4.z, a4.w};
      float bv[8] = {b0.x, b0.y, b0.z, b0.w, b1.x, b1.y, b1.z, b1.w};
#pragma unroll
      for (int i = 0; i < 4; ++i)
#pragma unroll
        for (int j = 0; j < 8; ++j) acc[i][j] = fmaf(av[i], bv[j], acc[i][j]);
    }
  }
#pragma unroll
  for (int j = 0; j < 8; ++j) {
    int cc = c8 + j;
    size_t base = (((size_t)(b * 128 + cc) * 64) + oy) * 64 + t4;
    float4 r = *(const float4*)&yds[base];
    *(float4*)&out[base] = make_float4(acc[0][j] + r.x, acc[1][j] + r.y,
                                       acc[2][j] + r.z, acc[3][j] + r.w);
  }
}

// =============== launch ===============
extern "C" void kernel_launch(void* const* d_in, const int* in_sizes, int n_in,
                              void* d_out, int out_size, void* d_ws, size_t ws_size,
                              hipStream_t stream) {
  (void)in_sizes; (void)n_in; (void)out_size; (void)ws_size;
  const float* x        = (const float*)d_in[0];
  const float* conv_w   = (const float*)d_in[1];
  const float* conv_b   = (const float*)d_in[2];
  const float* bn_g     = (const float*)d_in[3];
  const float* bn_b     = (const float*)d_in[4];
  const float* bn_mean  = (const float*)d_in[5];
  const float* bn_var   = (const float*)d_in[6];
  const float* in_w     = (const float*)d_in[7];
  const float* conv1d_w = (const float*)d_in[8];
  const float* conv1d_b = (const float*)d_in[9];
  const float* xproj_w  = (const float*)d_in[10];
  const float* dtproj_w = (const float*)d_in[11];
  const float* dtproj_b = (const float*)d_in[12];
  const float* A_log    = (const float*)d_in[13];
  const float* Dp       = (const float*)d_in[14];
  const float* out_w    = (const float*)d_in[15];
  float* ws = (float*)d_ws;
  float* out = (float*)d_out;

  k0_prep<<<329, 256, 0, stream>>>(conv_w, conv_b, bn_g, bn_b, bn_mean, bn_var,
                                   xproj_w, ws);
  k1_conv_bn_gelu<<<1024, 256, 0, stream>>>(x, ws + OFF_WT, ws + OFF_BIAS2,
                                            ws + OFF_YDS);
  k2_inproj<<<2048, 256, 0, stream>>>(ws + OFF_YDS, in_w, ws + OFF_XPRE, ws + OFF_Z);
  k3_conv1d_silu<<<4096, 256, 0, stream>>>(ws + OFF_XPRE, conv1d_w, conv1d_b,
                                           ws + OFF_XIN);
  k4_xproj_delta<<<256, 256, 0, stream>>>(ws + OFF_XIN, ws + OFF_XWT, dtproj_w,
                                          dtproj_b, ws + OFF_DELTA, ws + OFF_BC);
  k5a_scan1<<<512, 256, 0, stream>>>(ws + OFF_DELTA, ws + OFF_XIN, ws + OFF_BC,
                                     A_log, ws + OFF_S, ws + OFF_DSUM);
  k5b_combine<<<64, 256, 0, stream>>>(ws + OFF_S, ws + OFF_DSUM, A_log);
  k5c_scan2<<<512, 256, 0, stream>>>(ws + OFF_DELTA, ws + OFF_XIN, ws + OFF_BC,
                                     ws + OFF_Z, A_log, Dp, ws + OFF_S,
                                     ws + OFF_YACT);
  k6_outproj<<<256, 256, 0, stream>>>(ws + OFF_YACT, out_w, ws + OFF_YDS, out);
}

// Round 4
// 336.479 us; speedup vs baseline: 1.8729x; 1.1674x over previous
//
#include <hip/hip_runtime.h>
#include <math.h>

// ---------------- problem sizes ----------------
#define NB 4
#define LTOK 4096
#define DM 128
#define DI 256
#define NCH 128    // scan chunks
#define TCH 32     // steps per chunk
#define GSZ 16     // chunks per combine group
#define NG  8      // groups = NCH/GSZ

// ---------------- workspace layout (float offsets) ----------------
// mamba intermediates t-major: [b][t][e]
#define OFF_WT     0u          // conv weights * bn_inv [64ci][9tap][128co]
#define OFF_BIAS2  73728u      // folded conv+bn bias [128]
#define OFF_XWT    73856u      // xproj_w transposed [256k][40e]
#define OFF_YDS    84096u      // gelu output [4][128][64][64]   (2097152)
#define OFF_XPRE   2181248u    // [4][4096][256]
#define OFF_Z      6375552u    // [4][4096][256]
#define OFF_XIN    10569856u   // [4][4096][256]
#define OFF_BC     14764160u   // [4][4096][44]: 0-7 dt, 8-23 B, 24-39 C (720896)
#define OFF_S      15485056u   // [4][128c][16n][256d] (2097152); becomes hinit_local
#define OFF_DSUM   17582208u   // [4][128c][256d] (131072)
#define OFF_GS     17713280u   // [4][8g][16n][256d] (131072); becomes ginit
#define OFF_GD     17844352u   // [4][8g][256d] (8192)
#define OFF_YACT   OFF_XPRE    // xpre dead after k3; reuse
// total 17852544 floats = 71.4 MB (< proven 80 MB budget)

#define DEV __device__ __forceinline__
#define L2E 1.4426950408889634f

DEV float fast_silu(float v) {
  return v * __builtin_amdgcn_rcpf(1.f + __expf(-v));
}

// =============== K0: fold BN into conv weights; transpose xproj_w ===============
__global__ __launch_bounds__(256) void k0_prep(
    const float* __restrict__ conv_w, const float* __restrict__ conv_b,
    const float* __restrict__ bn_g, const float* __restrict__ bn_b,
    const float* __restrict__ bn_mean, const float* __restrict__ bn_var,
    const float* __restrict__ xproj_w, float* __restrict__ ws) {
  int i = blockIdx.x * 256 + threadIdx.x;
  if (i < 73728) {
    int co = i & 127; int tap = (i >> 7) % 9; int ci = i / 1152;
    float inv = bn_g[co] * rsqrtf(bn_var[co] + 1e-5f);
    ws[OFF_WT + i] = conv_w[co * 576 + ci * 9 + tap] * inv;
  } else if (i < 73728 + 10240) {
    int j = i - 73728; int e = j % 40; int k = j / 40;
    ws[OFF_XWT + j] = xproj_w[e * 256 + k];
  } else if (i < 73728 + 10240 + 128) {
    int co = i - 73728 - 10240;
    float inv = bn_g[co] * rsqrtf(bn_var[co] + 1e-5f);
    ws[OFF_BIAS2 + co] = (conv_b[co] - bn_mean[co]) * inv + bn_b[co];
  }
}

// =============== K1: conv3x3 s2 + BN + exact GELU ===============
__global__ __launch_bounds__(256) void k1_conv_bn_gelu(
    const float* __restrict__ x, const float* __restrict__ wt,
    const float* __restrict__ bias2, float* __restrict__ yds) {
  __shared__ float e_lds[16][3][66];
  __shared__ float o_lds[16][3][66];
  const int tid = threadIdx.x;
  const int ox = tid & 63;
  const int wv = __builtin_amdgcn_readfirstlane(tid >> 6);
  const int cog = blockIdx.x & 3;
  const int oy = (blockIdx.x >> 2) & 63;
  const int b = blockIdx.x >> 8;
  const int iy0 = 2 * oy - 1;
  const int cobase = cog * 32 + wv * 8;
  float acc[8];
#pragma unroll
  for (int j = 0; j < 8; ++j) acc[j] = 0.f;

  for (int c = 0; c < 4; ++c) {
    const int ci0 = c * 16;
    __syncthreads();
    for (int idx = tid; idx < 16 * 3 * 32; idx += 256) {
      int cc = idx / 96; int rem = idx % 96; int r = rem >> 5; int xq = rem & 31;
      int iy = iy0 + r;
      float4 v = make_float4(0.f, 0.f, 0.f, 0.f);
      if (iy >= 0)
        v = *(const float4*)&x[(((size_t)(b * 64 + ci0 + cc) * 128) + iy) * 128 + xq * 4];
      e_lds[cc][r][2 * xq + 0] = v.x; e_lds[cc][r][2 * xq + 1] = v.z;
      o_lds[cc][r][2 * xq + 1] = v.y; o_lds[cc][r][2 * xq + 2] = v.w;
      if (xq == 0) o_lds[cc][r][0] = 0.f;
    }
    __syncthreads();
#pragma unroll 1
    for (int cc = 0; cc < 16; ++cc) {
#pragma unroll
      for (int kh = 0; kh < 3; ++kh) {
        float v0 = o_lds[cc][kh][ox];
        float v1 = e_lds[cc][kh][ox];
        float v2 = o_lds[cc][kh][ox + 1];
        const float* w0 = &wt[((ci0 + cc) * 9 + kh * 3 + 0) * 128 + cobase];
        const float* w1 = w0 + 128;
        const float* w2 = w0 + 256;
#pragma unroll
        for (int j = 0; j < 8; ++j) {
          acc[j] = fmaf(v0, w0[j], acc[j]);
          acc[j] = fmaf(v1, w1[j], acc[j]);
          acc[j] = fmaf(v2, w2[j], acc[j]);
        }
      }
    }
  }
#pragma unroll
  for (int j = 0; j < 8; ++j) {
    float v = acc[j] + bias2[cobase + j];
    float g = 0.5f * v * (1.f + erff(v * 0.70710678118f));
    yds[(((size_t)(b * 128 + cobase + j) * 64) + oy) * 64 + ox] = g;
  }
}

// =============== K2: in_proj GEMM -> t-major xpre, z ===============
__global__ __launch_bounds__(256) void k2_inproj(
    const float* __restrict__ yds, const float* __restrict__ in_w,
    float* __restrict__ xpre, float* __restrict__ z) {
  __shared__ __align__(16) float a_lds[64][68];
  __shared__ __align__(16) float w_lds[64][68];
  const int tid = threadIdx.x;
  const int et = blockIdx.x & 7;
  const int rowid = blockIdx.x >> 3;
  const int oy = rowid & 63, b = rowid >> 6;
  const int t4 = (tid & 15) * 4, e4 = (tid >> 4) * 4;
  float acc[4][4];
#pragma unroll
  for (int i = 0; i < 4; ++i)
#pragma unroll
    for (int j = 0; j < 4; ++j) acc[i][j] = 0.f;

  for (int kc = 0; kc < 2; ++kc) {
    __syncthreads();
    for (int idx = tid; idx < 1024; idx += 256) {
      int k = idx >> 4, tq = idx & 15;
      *(float4*)&a_lds[k][tq * 4] =
          *(const float4*)&yds[(((size_t)(b * 128 + kc * 64 + k) * 64) + oy) * 64 + tq * 4];
    }
    for (int idx = tid; idx < 1024; idx += 256) {
      int j = idx >> 4, kq = idx & 15;
      float4 v = *(const float4*)&in_w[(size_t)(et * 64 + j) * 128 + kc * 64 + kq * 4];
      w_lds[kq * 4 + 0][j] = v.x; w_lds[kq * 4 + 1][j] = v.y;
      w_lds[kq * 4 + 2][j] = v.z; w_lds[kq * 4 + 3][j] = v.w;
    }
    __syncthreads();
#pragma unroll 8
    for (int k = 0; k < 64; ++k) {
      float4 a4 = *(const float4*)&a_lds[k][t4];
      float4 b4 = *(const float4*)&w_lds[k][e4];
      float av[4] = {a4.x, a4.y, a4.z, a4.w};
      float bv[4] = {b4.x, b4.y, b4.z, b4.w};
#pragma unroll
      for (int i = 0; i < 4; ++i)
#pragma unroll
        for (int j = 0; j < 4; ++j) acc[i][j] = fmaf(av[i], bv[j], acc[i][j]);
    }
  }
  const int e0 = et * 64 + e4;
#pragma unroll
  for (int i = 0; i < 4; ++i) {
    int t = oy * 64 + t4 + i;
    float4 v = make_float4(acc[i][0], acc[i][1], acc[i][2], acc[i][3]);
    float* dst = (e0 < 256) ? (xpre + ((size_t)(b * 4096 + t)) * 256 + e0)
                            : (z + ((size_t)(b * 4096 + t)) * 256 + (e0 - 256));
    *(float4*)dst = v;
  }
}

// =============== K3: depthwise causal conv1d (k=4) + SiLU, t-major ===============
__global__ __launch_bounds__(256) void k3_conv1d_silu(
    const float* __restrict__ xpre, const float* __restrict__ w,
    const float* __restrict__ bvec, float* __restrict__ xin) {
  int i = blockIdx.x * 256 + threadIdx.x;
  int e4 = (i & 63) * 4;
  int t = (i >> 6) & 4095;
  int b = i >> 18;
  const float* base = xpre + (size_t)b * 4096 * 256;
  float4 zero = make_float4(0.f, 0.f, 0.f, 0.f);
  float4 r0 = (t >= 3) ? *(const float4*)&base[(size_t)(t - 3) * 256 + e4] : zero;
  float4 r1 = (t >= 2) ? *(const float4*)&base[(size_t)(t - 2) * 256 + e4] : zero;
  float4 r2 = (t >= 1) ? *(const float4*)&base[(size_t)(t - 1) * 256 + e4] : zero;
  float4 r3 = *(const float4*)&base[(size_t)t * 256 + e4];
  float4 w0 = *(const float4*)&w[(e4 + 0) * 4];
  float4 w1 = *(const float4*)&w[(e4 + 1) * 4];
  float4 w2 = *(const float4*)&w[(e4 + 2) * 4];
  float4 w3 = *(const float4*)&w[(e4 + 3) * 4];
  float4 bv = *(const float4*)&bvec[e4];
  float o0 = bv.x + w0.x * r0.x + w0.y * r1.x + w0.z * r2.x + w0.w * r3.x;
  float o1 = bv.y + w1.x * r0.y + w1.y * r1.y + w1.z * r2.y + w1.w * r3.y;
  float o2 = bv.z + w2.x * r0.z + w2.y * r1.z + w2.z * r2.z + w2.w * r3.z;
  float o3 = bv.w + w3.x * r0.w + w3.y * r1.w + w3.z * r2.w + w3.w * r3.w;
  *(float4*)&xin[((size_t)b * 4096 + t) * 256 + e4] =
      make_float4(fast_silu(o0), fast_silu(o1), fast_silu(o2), fast_silu(o3));
}

// =============== K4: x_proj GEMM (K=256,N=40) -> bc[b][t][44] raw ===============
__global__ __launch_bounds__(256) void k4_xproj(
    const float* __restrict__ xin, const float* __restrict__ xwt,
    float* __restrict__ bc) {
  __shared__ float a_lds[128][65];     // [e][t] transposed
  __shared__ float xdbl[40][68];
  const int tid = threadIdx.x;
  const int t = tid & 63;
  const int wv = __builtin_amdgcn_readfirstlane(tid >> 6);
  const int tt = blockIdx.x & 63, b = blockIdx.x >> 6;
  const int t0 = tt * 64;
  float acc[10];
#pragma unroll
  for (int j = 0; j < 10; ++j) acc[j] = 0.f;

  for (int kh2 = 0; kh2 < 2; ++kh2) {
    __syncthreads();
    for (int idx = tid; idx < 2048; idx += 256) {
      int tl = idx >> 5; int e4 = (idx & 31) * 4;
      float4 v = *(const float4*)&xin[((size_t)(b * 4096 + t0 + tl)) * 256 + kh2 * 128 + e4];
      a_lds[e4 + 0][tl] = v.x; a_lds[e4 + 1][tl] = v.y;
      a_lds[e4 + 2][tl] = v.z; a_lds[e4 + 3][tl] = v.w;
    }
    __syncthreads();
#pragma unroll 4
    for (int k = 0; k < 128; ++k) {
      float av = a_lds[k][t];
      const float* wrow = &xwt[(kh2 * 128 + k) * 40 + wv * 10];
#pragma unroll
      for (int j = 0; j < 10; ++j) acc[j] = fmaf(av, wrow[j], acc[j]);
    }
  }
#pragma unroll
  for (int j = 0; j < 10; ++j) xdbl[wv * 10 + j][t] = acc[j];
  __syncthreads();
  // write 40 cols (0-7 dt raw, 8-23 B, 24-39 C) into 44-wide rows
  for (int idx = tid; idx < 2560; idx += 256) {
    int tl = idx / 40, col = idx - tl * 40;
    bc[((size_t)(b * 4096 + t0 + tl)) * 44 + col] = xdbl[col][tl];
  }
}

// =============== scan common: softplus(dt.w + bias) ===============
DEV float softplus_dot(const float4& t0v, const float4& t1v,
                       const float4& wa, const float4& wb, float bias) {
  float s = bias;
  s = fmaf(t0v.x, wa.x, s); s = fmaf(t0v.y, wa.y, s);
  s = fmaf(t0v.z, wa.z, s); s = fmaf(t0v.w, wa.w, s);
  s = fmaf(t1v.x, wb.x, s); s = fmaf(t1v.y, wb.y, s);
  s = fmaf(t1v.z, wb.z, s); s = fmaf(t1v.w, wb.w, s);
  return fmaxf(s, 0.f) + log1pf(__expf(-fabsf(s)));
}

// =============== K5a: pass 1 -> S[b][c][n][d] chunk-local scan + dsum ===============
// block = one (b, chunk); thread = d (0..255); h[16] n-states in registers.
__global__ __launch_bounds__(256) void k5a_scan1(
    const float* __restrict__ xin, const float* __restrict__ bc,
    const float* __restrict__ A_log, const float* __restrict__ dtw,
    const float* __restrict__ dtb, float* __restrict__ S,
    float* __restrict__ dsum) {
  __shared__ __align__(16) float bct[TCH * 44];
  const int tid = threadIdx.x;
  const int d = tid;
  const int c = blockIdx.x & (NCH - 1), b = blockIdx.x >> 7;
  const int t0 = c * TCH;
  {
    const float* src = bc + (size_t)(b * 4096 + t0) * 44;
    for (int i = tid; i < TCH * 44; i += 256) bct[i] = src[i];
  }
  float A2[16];
#pragma unroll
  for (int j = 0; j < 4; ++j) {
    float4 a = *(const float4*)&A_log[d * 16 + j * 4];
    A2[4 * j + 0] = -__expf(a.x) * L2E; A2[4 * j + 1] = -__expf(a.y) * L2E;
    A2[4 * j + 2] = -__expf(a.z) * L2E; A2[4 * j + 3] = -__expf(a.w) * L2E;
  }
  float4 wa = *(const float4*)&dtw[d * 8];
  float4 wb = *(const float4*)&dtw[d * 8 + 4];
  const float bias = dtb[d];
  float h[16];
#pragma unroll
  for (int n = 0; n < 16; ++n) h[n] = 0.f;
  float ds = 0.f;
  const float* px = xin + (size_t)(b * 4096 + t0) * 256 + d;
  __syncthreads();
#pragma unroll 2
  for (int i = 0; i < TCH; ++i) {
    float xv = px[(size_t)i * 256];
    const float* r = &bct[i * 44];
    float4 t0v = *(const float4*)&r[0];
    float4 t1v = *(const float4*)&r[4];
    float dl = softplus_dot(t0v, t1v, wa, wb, bias);
    ds += dl;
    float dlx = dl * xv;
    float4 B0 = *(const float4*)&r[8];
    float4 B1 = *(const float4*)&r[12];
    float4 B2 = *(const float4*)&r[16];
    float4 B3 = *(const float4*)&r[20];
    float Bv[16] = {B0.x, B0.y, B0.z, B0.w, B1.x, B1.y, B1.z, B1.w,
                    B2.x, B2.y, B2.z, B2.w, B3.x, B3.y, B3.z, B3.w};
#pragma unroll
    for (int n = 0; n < 16; ++n)
      h[n] = fmaf(exp2f(dl * A2[n]), h[n], dlx * Bv[n]);
  }
  const int sbase = ((b * NCH + c) * 16) * 256 + d;
#pragma unroll
  for (int n = 0; n < 16; ++n) S[sbase + n * 256] = h[n];
  dsum[(b * NCH + c) * 256 + d] = ds;
}

// =============== K5b1: within-group combine; hinit_local in-place; group totals ===============
__global__ __launch_bounds__(256) void k5b1_group(
    float* __restrict__ S, const float* __restrict__ dsum,
    const float* __restrict__ A_log, float* __restrict__ Gs,
    float* __restrict__ Gd) {
  const int d = threadIdx.x;
  const int n = blockIdx.x & 15, g = (blockIdx.x >> 4) & (NG - 1),
            b = blockIdx.x >> 7;
  const float A2 = -__expf(A_log[d * 16 + n]) * L2E;
  float h = 0.f, cum = 0.f;
#pragma unroll 4
  for (int c16 = 0; c16 < GSZ; ++c16) {
    int c = (g << 4) + c16;
    int si = ((b * NCH + c) * 16 + n) * 256 + d;
    float s = S[si];
    float dsv = dsum[(b * NCH + c) * 256 + d];
    float P = exp2f(A2 * dsv);
    S[si] = h;                       // exclusive prefix within group
    h = fmaf(P, h, s);
    cum += dsv;
  }
  Gs[((b * NG + g) * 16 + n) * 256 + d] = h;
  if (n == 0) Gd[(b * NG + g) * 256 + d] = cum;
}

// =============== K5b2: scan group totals -> ginit in-place over Gs ===============
__global__ __launch_bounds__(256) void k5b2_groupscan(
    float* __restrict__ Gs, const float* __restrict__ Gd,
    const float* __restrict__ A_log) {
  const int d = threadIdx.x;
  const int n = blockIdx.x & 15, b = blockIdx.x >> 4;
  const float A2 = -__expf(A_log[d * 16 + n]) * L2E;
  float h = 0.f;
#pragma unroll
  for (int g = 0; g < NG; ++g) {
    int gi = ((b * NG + g) * 16 + n) * 256 + d;
    float s = Gs[gi];
    float P = exp2f(A2 * Gd[(b * NG + g) * 256 + d]);
    Gs[gi] = h;                      // exclusive group prefix
    h = fmaf(P, h, s);
  }
}

// =============== K5c: pass 2 -> y, fused (+x*Dp)*silu(z) epilogue ===============
__global__ __launch_bounds__(256) void k5c_scan2(
    const float* __restrict__ xin, const float* __restrict__ bc,
    const float* __restrict__ z, const float* __restrict__ A_log,
    const float* __restrict__ dtw, const float* __restrict__ dtb,
    const float* __restrict__ Dp, const float* __restrict__ S,
    const float* __restrict__ dsum, const float* __restrict__ Gs,
    float* __restrict__ yact) {
  __shared__ __align__(16) float bct[TCH * 44];
  const int tid = threadIdx.x;
  const int d = tid;
  const int c = blockIdx.x & (NCH - 1), b = blockIdx.x >> 7;
  const int t0 = c * TCH;
  {
    const float* src = bc + (size_t)(b * 4096 + t0) * 44;
    for (int i = tid; i < TCH * 44; i += 256) bct[i] = src[i];
  }
  float A2[16];
#pragma unroll
  for (int j = 0; j < 4; ++j) {
    float4 a = *(const float4*)&A_log[d * 16 + j * 4];
    A2[4 * j + 0] = -__expf(a.x) * L2E; A2[4 * j + 1] = -__expf(a.y) * L2E;
    A2[4 * j + 2] = -__expf(a.z) * L2E; A2[4 * j + 3] = -__expf(a.w) * L2E;
  }
  float4 wa = *(const float4*)&dtw[d * 8];
  float4 wb = *(const float4*)&dtw[d * 8 + 4];
  const float bias = dtb[d];
  const float Dpd = Dp[d];
  // h_start = Ppref_local * ginit + hinit_local
  const int g = c >> 4, c16 = c & 15;
  float dpref = 0.f;
  {
    const float* pds = dsum + (b * NCH + (g << 4)) * 256 + d;
    for (int cc = 0; cc < c16; ++cc) dpref += pds[cc * 256];
  }
  const int sbase = ((b * NCH + c) * 16) * 256 + d;
  const int gbase = ((b * NG + g) * 16) * 256 + d;
  float h[16];
#pragma unroll
  for (int n = 0; n < 16; ++n) {
    float gi = Gs[gbase + n * 256];
    float hl = S[sbase + n * 256];
    h[n] = fmaf(exp2f(A2[n] * dpref), gi, hl);
  }
  const size_t base = (size_t)(b * 4096 + t0) * 256 + d;
  const float* px = xin + base;
  const float* pz = z + base;
  float* py = yact + base;
  __syncthreads();
#pragma unroll 2
  for (int i = 0; i < TCH; ++i) {
    float xv = px[(size_t)i * 256];
    float zv = pz[(size_t)i * 256];
    const float* r = &bct[i * 44];
    float4 t0v = *(const float4*)&r[0];
    float4 t1v = *(const float4*)&r[4];
    float dl = softplus_dot(t0v, t1v, wa, wb, bias);
    float dlx = dl * xv;
    float4 B0 = *(const float4*)&r[8];
    float4 B1 = *(const float4*)&r[12];
    float4 B2 = *(const float4*)&r[16];
    float4 B3 = *(const float4*)&r[20];
    float4 C0 = *(const float4*)&r[24];
    float4 C1 = *(const float4*)&r[28];
    float4 C2 = *(const float4*)&r[32];
    float4 C3 = *(const float4*)&r[36];
    float Bv[16] = {B0.x, B0.y, B0.z, B0.w, B1.x, B1.y, B1.z, B1.w,
                    B2.x, B2.y, B2.z, B2.w, B3.x, B3.y, B3.z, B3.w};
    float Cv[16] = {C0.x, C0.y, C0.z, C0.w, C1.x, C1.y, C1.z, C1.w,
                    C2.x, C2.y, C2.z, C2.w, C3.x, C3.y, C3.z, C3.w};
    float y = 0.f;
#pragma unroll
    for (int n = 0; n < 16; ++n) {
      h[n] = fmaf(exp2f(dl * A2[n]), h[n], dlx * Bv[n]);
      y = fmaf(h[n], Cv[n], y);
    }
    py[(size_t)i * 256] = (y + xv * Dpd) * fast_silu(zv);
  }
}

// =============== K6: out_proj GEMM + residual ===============
__global__ __launch_bounds__(256) void k6_outproj(
    const float* __restrict__ yact, const float* __restrict__ out_w,
    const float* __restrict__ yds, float* __restrict__ out) {
  __shared__ __align__(16) float a_lds[64][68];
  __shared__ __align__(16) float w_lds[64][132];
  const int tid = threadIdx.x;
  const int oy = blockIdx.x & 63, b = blockIdx.x >> 6;
  const int t4 = (tid & 15) * 4, c8 = (tid >> 4) * 8;
  float acc[4][8];
#pragma unroll
  for (int i = 0; i < 4; ++i)
#pragma unroll
    for (int j = 0; j < 8; ++j) acc[i][j] = 0.f;

  for (int kc = 0; kc < 4; ++kc) {
    __syncthreads();
    for (int idx = tid; idx < 1024; idx += 256) {
      int tl = idx >> 4; int e4 = (idx & 15) * 4;
      float4 v = *(const float4*)&yact[((size_t)(b * 4096 + oy * 64 + tl)) * 256 + kc * 64 + e4];
      a_lds[e4 + 0][tl] = v.x; a_lds[e4 + 1][tl] = v.y;
      a_lds[e4 + 2][tl] = v.z; a_lds[e4 + 3][tl] = v.w;
    }
    for (int idx = tid; idx < 2048; idx += 256) {
      int cc = idx >> 4, kq = idx & 15;
      float4 v = *(const float4*)&out_w[(size_t)cc * 256 + kc * 64 + kq * 4];
      w_lds[kq * 4 + 0][cc] = v.x; w_lds[kq * 4 + 1][cc] = v.y;
      w_lds[kq * 4 + 2][cc] = v.z; w_lds[kq * 4 + 3][cc] = v.w;
    }
    __syncthreads();
#pragma unroll 4
    for (int k = 0; k < 64; ++k) {
      float4 a4 = *(const float4*)&a_lds[k][t4];
      float4 b0 = *(const float4*)&w_lds[k][c8];
      float4 b1 = *(const float4*)&w_lds[k][c8 + 4];
      float av[4] = {a4.x, a4.y, a4.z, a4.w};
      float bv[8] = {b0.x, b0.y, b0.z, b0.w, b1.x, b1.y, b1.z, b1.w};
#pragma unroll
      for (int i = 0; i < 4; ++i)
#pragma unroll
        for (int j = 0; j < 8; ++j) acc[i][j] = fmaf(av[i], bv[j], acc[i][j]);
    }
  }
#pragma unroll
  for (int j = 0; j < 8; ++j) {
    int cc = c8 + j;
    size_t base = (((size_t)(b * 128 + cc) * 64) + oy) * 64 + t4;
    float4 r = *(const float4*)&yds[base];
    *(float4*)&out[base] = make_float4(acc[0][j] + r.x, acc[1][j] + r.y,
                                       acc[2][j] + r.z, acc[3][j] + r.w);
  }
}

// =============== launch ===============
extern "C" void kernel_launch(void* const* d_in, const int* in_sizes, int n_in,
                              void* d_out, int out_size, void* d_ws, size_t ws_size,
                              hipStream_t stream) {
  (void)in_sizes; (void)n_in; (void)out_size; (void)ws_size;
  const float* x        = (const float*)d_in[0];
  const float* conv_w   = (const float*)d_in[1];
  const float* conv_b   = (const float*)d_in[2];
  const float* bn_g     = (const float*)d_in[3];
  const float* bn_b     = (const float*)d_in[4];
  const float* bn_mean  = (const float*)d_in[5];
  const float* bn_var   = (const float*)d_in[6];
  const float* in_w     = (const float*)d_in[7];
  const float* conv1d_w = (const float*)d_in[8];
  const float* conv1d_b = (const float*)d_in[9];
  const float* xproj_w  = (const float*)d_in[10];
  const float* dtproj_w = (const float*)d_in[11];
  const float* dtproj_b = (const float*)d_in[12];
  const float* A_log    = (const float*)d_in[13];
  const float* Dp       = (const float*)d_in[14];
  const float* out_w    = (const float*)d_in[15];
  float* ws = (float*)d_ws;
  float* out = (float*)d_out;

  k0_prep<<<329, 256, 0, stream>>>(conv_w, conv_b, bn_g, bn_b, bn_mean, bn_var,
                                   xproj_w, ws);
  k1_conv_bn_gelu<<<1024, 256, 0, stream>>>(x, ws + OFF_WT, ws + OFF_BIAS2,
                                            ws + OFF_YDS);
  k2_inproj<<<2048, 256, 0, stream>>>(ws + OFF_YDS, in_w, ws + OFF_XPRE, ws + OFF_Z);
  k3_conv1d_silu<<<4096, 256, 0, stream>>>(ws + OFF_XPRE, conv1d_w, conv1d_b,
                                           ws + OFF_XIN);
  k4_xproj<<<256, 256, 0, stream>>>(ws + OFF_XIN, ws + OFF_XWT, ws + OFF_BC);
  k5a_scan1<<<512, 256, 0, stream>>>(ws + OFF_XIN, ws + OFF_BC, A_log,
                                     dtproj_w, dtproj_b, ws + OFF_S, ws + OFF_DSUM);
  k5b1_group<<<512, 256, 0, stream>>>(ws + OFF_S, ws + OFF_DSUM, A_log,
                                      ws + OFF_GS, ws + OFF_GD);
  k5b2_groupscan<<<64, 256, 0, stream>>>(ws + OFF_GS, ws + OFF_GD, A_log);
  k5c_scan2<<<512, 256, 0, stream>>>(ws + OFF_XIN, ws + OFF_BC, ws + OFF_Z,
                                     A_log, dtproj_w, dtproj_b, Dp, ws + OFF_S,
                                     ws + OFF_DSUM, ws + OFF_GS, ws + OFF_YACT);
  k6_outproj<<<256, 256, 0, stream>>>(ws + OFF_YACT, out_w, ws + OFF_YDS, out);
}

// Round 5
// 314.478 us; speedup vs baseline: 2.0040x; 1.0700x over previous
//
#include <hip/hip_runtime.h>
#include <math.h>

// ---------------- problem sizes ----------------
#define NB 4
#define LTOK 4096
#define DM 128
#define DI 256
#define NCH 128    // scan chunks
#define TCH 32     // steps per chunk
#define GSZ 16     // chunks per combine group
#define NG  8      // groups = NCH/GSZ

// ---------------- workspace layout (float offsets) ----------------
// mamba intermediates t-major: [b][t][e]
#define OFF_WT     0u          // (unused legacy region)
#define OFF_BIAS2  73728u      // folded conv+bn bias [128]
#define OFF_XWT    73856u      // xproj_w transposed [256k][40e]
#define OFF_YDS    84096u      // gelu output [4][128][64][64]   (2097152)
#define OFF_XPRE   2181248u    // [4][4096][256]
#define OFF_Z      6375552u    // [4][4096][256]
#define OFF_XIN    10569856u   // [4][4096][256]
#define OFF_BC     14764160u   // [4][4096][44]: 0-7 dt, 8-23 B, 24-39 C (720896)
#define OFF_S      15485056u   // [4][128c][16n][256d] (2097152); becomes hinit_local
#define OFF_DSUM   17582208u   // [4][128c][256d] (131072)
#define OFF_GS     17713280u   // [4][8g][16n][256d] (131072); becomes ginit
#define OFF_GD     17844352u   // [4][8g][256d] (8192)
#define OFF_XT     17852544u   // bf16 x transposed [4][128iy][128ix][64ci] (2097152 fl)
#define OFF_WBF    19949696u   // bf16 conv weights*bn_inv [128co][9tap][64ci] (36864 fl)
#define OFF_YACT   OFF_XPRE    // xpre dead after k3; reuse
// total 19986560 floats = 79.9 MB (< proven 80.2 MB budget)

#define DEV __device__ __forceinline__
#define L2E 1.4426950408889634f

typedef short bh8 __attribute__((ext_vector_type(8)));   // 8 bf16 (4 VGPR)
typedef float f4v __attribute__((ext_vector_type(4)));

DEV float fast_silu(float v) {
  return v * __builtin_amdgcn_rcpf(1.f + __expf(-v));
}

DEV unsigned short f2bf(float f) {                       // round-to-nearest-even
  unsigned int u = __float_as_uint(f);
  u = (u + 0x7FFFu + ((u >> 16) & 1u)) >> 16;
  return (unsigned short)u;
}

// =============== K0: fold BN into bf16 conv weights; transpose xproj_w ===============
__global__ __launch_bounds__(256) void k0_prep(
    const float* __restrict__ conv_w, const float* __restrict__ conv_b,
    const float* __restrict__ bn_g, const float* __restrict__ bn_b,
    const float* __restrict__ bn_mean, const float* __restrict__ bn_var,
    const float* __restrict__ xproj_w, float* __restrict__ ws) {
  int i = blockIdx.x * 256 + threadIdx.x;
  if (i < 73728) {
    // wbf[co][tap][ci] = bf16(conv_w[co][ci][tap] * bn_inv[co])
    int ci = i & 63; int tap = (i >> 6) % 9; int co = i / 576;
    float inv = bn_g[co] * rsqrtf(bn_var[co] + 1e-5f);
    ((unsigned short*)(ws + OFF_WBF))[i] = f2bf(conv_w[co * 576 + ci * 9 + tap] * inv);
  } else if (i < 73728 + 10240) {
    int j = i - 73728; int e = j % 40; int k = j / 40;
    ws[OFF_XWT + j] = xproj_w[e * 256 + k];
  } else if (i < 73728 + 10240 + 128) {
    int co = i - 73728 - 10240;
    float inv = bn_g[co] * rsqrtf(bn_var[co] + 1e-5f);
    ws[OFF_BIAS2 + co] = (conv_b[co] - bn_mean[co]) * inv + bn_b[co];
  }
}

// =============== K0b: transpose x -> xt[b][iy][ix][ci] bf16 ===============
__global__ __launch_bounds__(256) void k0b_transpose(
    const float* __restrict__ x, unsigned short* __restrict__ xt) {
  __shared__ float t[64][65];
  const int tid = threadIdx.x;
  const int ixh = blockIdx.x & 1;
  const int iy = (blockIdx.x >> 1) & 127;
  const int b = blockIdx.x >> 8;
  {
    const int ixl = tid & 63, cw = tid >> 6;
#pragma unroll 4
    for (int i = 0; i < 16; ++i) {
      int ci = cw * 16 + i;
      t[ci][ixl] = x[(((size_t)(b * 64 + ci) * 128) + iy) * 128 + ixh * 64 + ixl];
    }
  }
  __syncthreads();
  {
    const int cil = tid & 63, iw = tid >> 6;
    unsigned short* dst = xt + (((size_t)(b * 128 + iy) * 128) + ixh * 64) * 64;
#pragma unroll 4
    for (int i = 0; i < 16; ++i) {
      int ix = iw * 16 + i;
      dst[ix * 64 + cil] = f2bf(t[cil][ix]);
    }
  }
}

// =============== K1: conv3x3 s2 + BN + GELU via bf16 MFMA ===============
// Tap-decomposed GEMM: C[co][tok] += W_tap[co][ci] * X[ci][2*tok-1+kw], K=9*64.
// grid 512 = (b=4, oy=64, cohalf=2); 4 waves; wave w: co0=cohalf*64+(w&1)*32,
// tok0=(w>>1)*32; 2x2 tiles of mfma_f32_16x16x32_bf16. No LDS, no barriers.
__global__ __launch_bounds__(256) void k1_conv_mfma(
    const unsigned short* __restrict__ xt, const unsigned short* __restrict__ wbf,
    const float* __restrict__ bias2, float* __restrict__ yds) {
  const int tid = threadIdx.x;
  const int lane = tid & 63;
  const int w = tid >> 6;
  const int col = lane & 15, quad = lane >> 4;
  const int cohalf = blockIdx.x & 1;
  const int oy = (blockIdx.x >> 1) & 63;
  const int b = blockIdx.x >> 7;
  const int co0 = cohalf * 64 + (w & 1) * 32;
  const int tok0 = (w >> 1) * 32;
  const int iy0 = 2 * oy - 1;
  const bh8 bzero = {};
  f4v acc[2][2];
#pragma unroll
  for (int mt = 0; mt < 2; ++mt)
#pragma unroll
    for (int nt = 0; nt < 2; ++nt) acc[mt][nt] = (f4v){0.f, 0.f, 0.f, 0.f};

  const unsigned short* ap0 = wbf + (size_t)(co0 + col) * 576;        // [tap][ci]
  const unsigned short* ap1 = wbf + (size_t)(co0 + 16 + col) * 576;

  for (int tap = 0; tap < 9; ++tap) {
    const int kh = tap / 3, kw = tap - kh * 3;
    const int iy = iy0 + kh;
    const int ix0 = 2 * (tok0 + col) - 1 + kw;   // n-tile 0 column
    const int ix1 = ix0 + 32;                    // n-tile 1 column
    const unsigned short* xrow = xt + (long)(b * 128 + iy) * 8192;
    const bool ok0 = (iy >= 0) && (ix0 >= 0);
    const bool ok1 = (iy >= 0);
#pragma unroll
    for (int kc = 0; kc < 2; ++kc) {
      const int cib = kc * 32 + quad * 8;
      bh8 a0 = *(const bh8*)&ap0[tap * 64 + cib];
      bh8 a1 = *(const bh8*)&ap1[tap * 64 + cib];
      bh8 b0 = *(const bh8*)&xrow[(long)ix0 * 64 + cib];
      bh8 b1 = *(const bh8*)&xrow[(long)ix1 * 64 + cib];
      if (!ok0) b0 = bzero;
      if (!ok1) b1 = bzero;
      acc[0][0] = __builtin_amdgcn_mfma_f32_16x16x32_bf16(a0, b0, acc[0][0], 0, 0, 0);
      acc[1][0] = __builtin_amdgcn_mfma_f32_16x16x32_bf16(a1, b0, acc[1][0], 0, 0, 0);
      acc[0][1] = __builtin_amdgcn_mfma_f32_16x16x32_bf16(a0, b1, acc[0][1], 0, 0, 0);
      acc[1][1] = __builtin_amdgcn_mfma_f32_16x16x32_bf16(a1, b1, acc[1][1], 0, 0, 0);
    }
  }
  // C/D layout: row = quad*4 + r (co), col = lane&15 (tok)
#pragma unroll
  for (int mt = 0; mt < 2; ++mt)
#pragma unroll
    for (int nt = 0; nt < 2; ++nt) {
      const int tok = tok0 + nt * 16 + col;
#pragma unroll
      for (int r = 0; r < 4; ++r) {
        const int co = co0 + mt * 16 + quad * 4 + r;
        float v = acc[mt][nt][r] + bias2[co];
        float g = 0.5f * v * (1.f + erff(v * 0.70710678118f));
        yds[(((size_t)(b * 128 + co) * 64) + oy) * 64 + tok] = g;
      }
    }
}

// =============== K2: in_proj GEMM -> t-major xpre, z ===============
__global__ __launch_bounds__(256) void k2_inproj(
    const float* __restrict__ yds, const float* __restrict__ in_w,
    float* __restrict__ xpre, float* __restrict__ z) {
  __shared__ __align__(16) float a_lds[64][68];
  __shared__ __align__(16) float w_lds[64][68];
  const int tid = threadIdx.x;
  const int et = blockIdx.x & 7;
  const int rowid = blockIdx.x >> 3;
  const int oy = rowid & 63, b = rowid >> 6;
  const int t4 = (tid & 15) * 4, e4 = (tid >> 4) * 4;
  float acc[4][4];
#pragma unroll
  for (int i = 0; i < 4; ++i)
#pragma unroll
    for (int j = 0; j < 4; ++j) acc[i][j] = 0.f;

  for (int kc = 0; kc < 2; ++kc) {
    __syncthreads();
    for (int idx = tid; idx < 1024; idx += 256) {
      int k = idx >> 4, tq = idx & 15;
      *(float4*)&a_lds[k][tq * 4] =
          *(const float4*)&yds[(((size_t)(b * 128 + kc * 64 + k) * 64) + oy) * 64 + tq * 4];
    }
    for (int idx = tid; idx < 1024; idx += 256) {
      int j = idx >> 4, kq = idx & 15;
      float4 v = *(const float4*)&in_w[(size_t)(et * 64 + j) * 128 + kc * 64 + kq * 4];
      w_lds[kq * 4 + 0][j] = v.x; w_lds[kq * 4 + 1][j] = v.y;
      w_lds[kq * 4 + 2][j] = v.z; w_lds[kq * 4 + 3][j] = v.w;
    }
    __syncthreads();
#pragma unroll 8
    for (int k = 0; k < 64; ++k) {
      float4 a4 = *(const float4*)&a_lds[k][t4];
      float4 b4 = *(const float4*)&w_lds[k][e4];
      float av[4] = {a4.x, a4.y, a4.z, a4.w};
      float bv[4] = {b4.x, b4.y, b4.z, b4.w};
#pragma unroll
      for (int i = 0; i < 4; ++i)
#pragma unroll
        for (int j = 0; j < 4; ++j) acc[i][j] = fmaf(av[i], bv[j], acc[i][j]);
    }
  }
  const int e0 = et * 64 + e4;
#pragma unroll
  for (int i = 0; i < 4; ++i) {
    int t = oy * 64 + t4 + i;
    float4 v = make_float4(acc[i][0], acc[i][1], acc[i][2], acc[i][3]);
    float* dst = (e0 < 256) ? (xpre + ((size_t)(b * 4096 + t)) * 256 + e0)
                            : (z + ((size_t)(b * 4096 + t)) * 256 + (e0 - 256));
    *(float4*)dst = v;
  }
}

// =============== K3: depthwise causal conv1d (k=4) + SiLU, t-major ===============
__global__ __launch_bounds__(256) void k3_conv1d_silu(
    const float* __restrict__ xpre, const float* __restrict__ w,
    const float* __restrict__ bvec, float* __restrict__ xin) {
  int i = blockIdx.x * 256 + threadIdx.x;
  int e4 = (i & 63) * 4;
  int t = (i >> 6) & 4095;
  int b = i >> 18;
  const float* base = xpre + (size_t)b * 4096 * 256;
  float4 zero = make_float4(0.f, 0.f, 0.f, 0.f);
  float4 r0 = (t >= 3) ? *(const float4*)&base[(size_t)(t - 3) * 256 + e4] : zero;
  float4 r1 = (t >= 2) ? *(const float4*)&base[(size_t)(t - 2) * 256 + e4] : zero;
  float4 r2 = (t >= 1) ? *(const float4*)&base[(size_t)(t - 1) * 256 + e4] : zero;
  float4 r3 = *(const float4*)&base[(size_t)t * 256 + e4];
  float4 w0 = *(const float4*)&w[(e4 + 0) * 4];
  float4 w1 = *(const float4*)&w[(e4 + 1) * 4];
  float4 w2 = *(const float4*)&w[(e4 + 2) * 4];
  float4 w3 = *(const float4*)&w[(e4 + 3) * 4];
  float4 bv = *(const float4*)&bvec[e4];
  float o0 = bv.x + w0.x * r0.x + w0.y * r1.x + w0.z * r2.x + w0.w * r3.x;
  float o1 = bv.y + w1.x * r0.y + w1.y * r1.y + w1.z * r2.y + w1.w * r3.y;
  float o2 = bv.z + w2.x * r0.z + w2.y * r1.z + w2.z * r2.z + w2.w * r3.z;
  float o3 = bv.w + w3.x * r0.w + w3.y * r1.w + w3.z * r2.w + w3.w * r3.w;
  *(float4*)&xin[((size_t)b * 4096 + t) * 256 + e4] =
      make_float4(fast_silu(o0), fast_silu(o1), fast_silu(o2), fast_silu(o3));
}

// =============== K4: x_proj GEMM (K=256,N=40) -> bc[b][t][44] raw ===============
__global__ __launch_bounds__(256) void k4_xproj(
    const float* __restrict__ xin, const float* __restrict__ xwt,
    float* __restrict__ bc) {
  __shared__ float a_lds[128][65];     // [e][t] transposed
  __shared__ float xdbl[40][68];
  const int tid = threadIdx.x;
  const int t = tid & 63;
  const int wv = __builtin_amdgcn_readfirstlane(tid >> 6);
  const int tt = blockIdx.x & 63, b = blockIdx.x >> 6;
  const int t0 = tt * 64;
  float acc[10];
#pragma unroll
  for (int j = 0; j < 10; ++j) acc[j] = 0.f;

  for (int kh2 = 0; kh2 < 2; ++kh2) {
    __syncthreads();
    for (int idx = tid; idx < 2048; idx += 256) {
      int tl = idx >> 5; int e4 = (idx & 31) * 4;
      float4 v = *(const float4*)&xin[((size_t)(b * 4096 + t0 + tl)) * 256 + kh2 * 128 + e4];
      a_lds[e4 + 0][tl] = v.x; a_lds[e4 + 1][tl] = v.y;
      a_lds[e4 + 2][tl] = v.z; a_lds[e4 + 3][tl] = v.w;
    }
    __syncthreads();
#pragma unroll 4
    for (int k = 0; k < 128; ++k) {
      float av = a_lds[k][t];
      const float* wrow = &xwt[(kh2 * 128 + k) * 40 + wv * 10];
#pragma unroll
      for (int j = 0; j < 10; ++j) acc[j] = fmaf(av, wrow[j], acc[j]);
    }
  }
#pragma unroll
  for (int j = 0; j < 10; ++j) xdbl[wv * 10 + j][t] = acc[j];
  __syncthreads();
  // write 40 cols (0-7 dt raw, 8-23 B, 24-39 C) into 44-wide rows
  for (int idx = tid; idx < 2560; idx += 256) {
    int tl = idx / 40, col = idx - tl * 40;
    bc[((size_t)(b * 4096 + t0 + tl)) * 44 + col] = xdbl[col][tl];
  }
}

// =============== scan common: softplus(dt.w + bias) ===============
DEV float softplus_dot(const float4& t0v, const float4& t1v,
                       const float4& wa, const float4& wb, float bias) {
  float s = bias;
  s = fmaf(t0v.x, wa.x, s); s = fmaf(t0v.y, wa.y, s);
  s = fmaf(t0v.z, wa.z, s); s = fmaf(t0v.w, wa.w, s);
  s = fmaf(t1v.x, wb.x, s); s = fmaf(t1v.y, wb.y, s);
  s = fmaf(t1v.z, wb.z, s); s = fmaf(t1v.w, wb.w, s);
  return fmaxf(s, 0.f) + log1pf(__expf(-fabsf(s)));
}

// =============== K5a: pass 1 -> S[b][c][n][d] chunk-local scan + dsum ===============
__global__ __launch_bounds__(256) void k5a_scan1(
    const float* __restrict__ xin, const float* __restrict__ bc,
    const float* __restrict__ A_log, const float* __restrict__ dtw,
    const float* __restrict__ dtb, float* __restrict__ S,
    float* __restrict__ dsum) {
  __shared__ __align__(16) float bct[TCH * 44];
  const int tid = threadIdx.x;
  const int d = tid;
  const int c = blockIdx.x & (NCH - 1), b = blockIdx.x >> 7;
  const int t0 = c * TCH;
  {
    const float* src = bc + (size_t)(b * 4096 + t0) * 44;
    for (int i = tid; i < TCH * 44; i += 256) bct[i] = src[i];
  }
  float A2[16];
#pragma unroll
  for (int j = 0; j < 4; ++j) {
    float4 a = *(const float4*)&A_log[d * 16 + j * 4];
    A2[4 * j + 0] = -__expf(a.x) * L2E; A2[4 * j + 1] = -__expf(a.y) * L2E;
    A2[4 * j + 2] = -__expf(a.z) * L2E; A2[4 * j + 3] = -__expf(a.w) * L2E;
  }
  float4 wa = *(const float4*)&dtw[d * 8];
  float4 wb = *(const float4*)&dtw[d * 8 + 4];
  const float bias = dtb[d];
  float h[16];
#pragma unroll
  for (int n = 0; n < 16; ++n) h[n] = 0.f;
  float ds = 0.f;
  const float* px = xin + (size_t)(b * 4096 + t0) * 256 + d;
  __syncthreads();
#pragma unroll 2
  for (int i = 0; i < TCH; ++i) {
    float xv = px[(size_t)i * 256];
    const float* r = &bct[i * 44];
    float4 t0v = *(const float4*)&r[0];
    float4 t1v = *(const float4*)&r[4];
    float dl = softplus_dot(t0v, t1v, wa, wb, bias);
    ds += dl;
    float dlx = dl * xv;
    float4 B0 = *(const float4*)&r[8];
    float4 B1 = *(const float4*)&r[12];
    float4 B2 = *(const float4*)&r[16];
    float4 B3 = *(const float4*)&r[20];
    float Bv[16] = {B0.x, B0.y, B0.z, B0.w, B1.x, B1.y, B1.z, B1.w,
                    B2.x, B2.y, B2.z, B2.w, B3.x, B3.y, B3.z, B3.w};
#pragma unroll
    for (int n = 0; n < 16; ++n)
      h[n] = fmaf(exp2f(dl * A2[n]), h[n], dlx * Bv[n]);
  }
  const int sbase = ((b * NCH + c) * 16) * 256 + d;
#pragma unroll
  for (int n = 0; n < 16; ++n) S[sbase + n * 256] = h[n];
  dsum[(b * NCH + c) * 256 + d] = ds;
}

// =============== K5b1: within-group combine; hinit_local in-place; group totals ===============
__global__ __launch_bounds__(256) void k5b1_group(
    float* __restrict__ S, const float* __restrict__ dsum,
    const float* __restrict__ A_log, float* __restrict__ Gs,
    float* __restrict__ Gd) {
  const int d = threadIdx.x;
  const int n = blockIdx.x & 15, g = (blockIdx.x >> 4) & (NG - 1),
            b = blockIdx.x >> 7;
  const float A2 = -__expf(A_log[d * 16 + n]) * L2E;
  float h = 0.f, cum = 0.f;
#pragma unroll 4
  for (int c16 = 0; c16 < GSZ; ++c16) {
    int c = (g << 4) + c16;
    int si = ((b * NCH + c) * 16 + n) * 256 + d;
    float s = S[si];
    float dsv = dsum[(b * NCH + c) * 256 + d];
    float P = exp2f(A2 * dsv);
    S[si] = h;                       // exclusive prefix within group
    h = fmaf(P, h, s);
    cum += dsv;
  }
  Gs[((b * NG + g) * 16 + n) * 256 + d] = h;
  if (n == 0) Gd[(b * NG + g) * 256 + d] = cum;
}

// =============== K5b2: scan group totals -> ginit in-place over Gs ===============
__global__ __launch_bounds__(256) void k5b2_groupscan(
    float* __restrict__ Gs, const float* __restrict__ Gd,
    const float* __restrict__ A_log) {
  const int d = threadIdx.x;
  const int n = blockIdx.x & 15, b = blockIdx.x >> 4;
  const float A2 = -__expf(A_log[d * 16 + n]) * L2E;
  float h = 0.f;
#pragma unroll
  for (int g = 0; g < NG; ++g) {
    int gi = ((b * NG + g) * 16 + n) * 256 + d;
    float s = Gs[gi];
    float P = exp2f(A2 * Gd[(b * NG + g) * 256 + d]);
    Gs[gi] = h;                      // exclusive group prefix
    h = fmaf(P, h, s);
  }
}

// =============== K5c: pass 2 -> y, fused (+x*Dp)*silu(z) epilogue ===============
__global__ __launch_bounds__(256) void k5c_scan2(
    const float* __restrict__ xin, const float* __restrict__ bc,
    const float* __restrict__ z, const float* __restrict__ A_log,
    const float* __restrict__ dtw, const float* __restrict__ dtb,
    const float* __restrict__ Dp, const float* __restrict__ S,
    const float* __restrict__ dsum, const float* __restrict__ Gs,
    float* __restrict__ yact) {
  __shared__ __align__(16) float bct[TCH * 44];
  const int tid = threadIdx.x;
  const int d = tid;
  const int c = blockIdx.x & (NCH - 1), b = blockIdx.x >> 7;
  const int t0 = c * TCH;
  {
    const float* src = bc + (size_t)(b * 4096 + t0) * 44;
    for (int i = tid; i < TCH * 44; i += 256) bct[i] = src[i];
  }
  float A2[16];
#pragma unroll
  for (int j = 0; j < 4; ++j) {
    float4 a = *(const float4*)&A_log[d * 16 + j * 4];
    A2[4 * j + 0] = -__expf(a.x) * L2E; A2[4 * j + 1] = -__expf(a.y) * L2E;
    A2[4 * j + 2] = -__expf(a.z) * L2E; A2[4 * j + 3] = -__expf(a.w) * L2E;
  }
  float4 wa = *(const float4*)&dtw[d * 8];
  float4 wb = *(const float4*)&dtw[d * 8 + 4];
  const float bias = dtb[d];
  const float Dpd = Dp[d];
  // h_start = exp2(A2*dpref_local) * ginit + hinit_local
  const int g = c >> 4, c16 = c & 15;
  float dpref = 0.f;
  {
    const float* pds = dsum + (b * NCH + (g << 4)) * 256 + d;
    for (int cc = 0; cc < c16; ++cc) dpref += pds[cc * 256];
  }
  const int sbase = ((b * NCH + c) * 16) * 256 + d;
  const int gbase = ((b * NG + g) * 16) * 256 + d;
  float h[16];
#pragma unroll
  for (int n = 0; n < 16; ++n) {
    float gi = Gs[gbase + n * 256];
    float hl = S[sbase + n * 256];
    h[n] = fmaf(exp2f(A2[n] * dpref), gi, hl);
  }
  const size_t base = (size_t)(b * 4096 + t0) * 256 + d;
  const float* px = xin + base;
  const float* pz = z + base;
  float* py = yact + base;
  __syncthreads();
#pragma unroll 2
  for (int i = 0; i < TCH; ++i) {
    float xv = px[(size_t)i * 256];
    float zv = pz[(size_t)i * 256];
    const float* r = &bct[i * 44];
    float4 t0v = *(const float4*)&r[0];
    float4 t1v = *(const float4*)&r[4];
    float dl = softplus_dot(t0v, t1v, wa, wb, bias);
    float dlx = dl * xv;
    float4 B0 = *(const float4*)&r[8];
    float4 B1 = *(const float4*)&r[12];
    float4 B2 = *(const float4*)&r[16];
    float4 B3 = *(const float4*)&r[20];
    float4 C0 = *(const float4*)&r[24];
    float4 C1 = *(const float4*)&r[28];
    float4 C2 = *(const float4*)&r[32];
    float4 C3 = *(const float4*)&r[36];
    float Bv[16] = {B0.x, B0.y, B0.z, B0.w, B1.x, B1.y, B1.z, B1.w,
                    B2.x, B2.y, B2.z, B2.w, B3.x, B3.y, B3.z, B3.w};
    float Cv[16] = {C0.x, C0.y, C0.z, C0.w, C1.x, C1.y, C1.z, C1.w,
                    C2.x, C2.y, C2.z, C2.w, C3.x, C3.y, C3.z, C3.w};
    float y = 0.f;
#pragma unroll
    for (int n = 0; n < 16; ++n) {
      h[n] = fmaf(exp2f(dl * A2[n]), h[n], dlx * Bv[n]);
      y = fmaf(h[n], Cv[n], y);
    }
    py[(size_t)i * 256] = (y + xv * Dpd) * fast_silu(zv);
  }
}

// =============== K6: out_proj GEMM + residual ===============
__global__ __launch_bounds__(256) void k6_outproj(
    const float* __restrict__ yact, const float* __restrict__ out_w,
    const float* __restrict__ yds, float* __restrict__ out) {
  __shared__ __align__(16) float a_lds[64][68];
  __shared__ __align__(16) float w_lds[64][132];
  const int tid = threadIdx.x;
  const int oy = blockIdx.x & 63, b = blockIdx.x >> 6;
  const int t4 = (tid & 15) * 4, c8 = (tid >> 4) * 8;
  float acc[4][8];
#pragma unroll
  for (int i = 0; i < 4; ++i)
#pragma unroll
    for (int j = 0; j < 8; ++j) acc[i][j] = 0.f;

  for (int kc = 0; kc < 4; ++kc) {
    __syncthreads();
    for (int idx = tid; idx < 1024; idx += 256) {
      int tl = idx >> 4; int e4 = (idx & 15) * 4;
      float4 v = *(const float4*)&yact[((size_t)(b * 4096 + oy * 64 + tl)) * 256 + kc * 64 + e4];
      a_lds[e4 + 0][tl] = v.x; a_lds[e4 + 1][tl] = v.y;
      a_lds[e4 + 2][tl] = v.z; a_lds[e4 + 3][tl] = v.w;
    }
    for (int idx = tid; idx < 2048; idx += 256) {
      int cc = idx >> 4, kq = idx & 15;
      float4 v = *(const float4*)&out_w[(size_t)cc * 256 + kc * 64 + kq * 4];
      w_lds[kq * 4 + 0][cc] = v.x; w_lds[kq * 4 + 1][cc] = v.y;
      w_lds[kq * 4 + 2][cc] = v.z; w_lds[kq * 4 + 3][cc] = v.w;
    }
    __syncthreads();
#pragma unroll 4
    for (int k = 0; k < 64; ++k) {
      float4 a4 = *(const float4*)&a_lds[k][t4];
      float4 b0 = *(const float4*)&w_lds[k][c8];
      float4 b1 = *(const float4*)&w_lds[k][c8 + 4];
      float av[4] = {a4.x, a4.y, a4.z, a4.w};
      float bv[8] = {b0.x, b0.y, b0.z, b0.w, b1.x, b1.y, b1.z, b1.w};
#pragma unroll
      for (int i = 0; i < 4; ++i)
#pragma unroll
        for (int j = 0; j < 8; ++j) acc[i][j] = fmaf(av[i], bv[j], acc[i][j]);
    }
  }
#pragma unroll
  for (int j = 0; j < 8; ++j) {
    int cc = c8 + j;
    size_t base = (((size_t)(b * 128 + cc) * 64) + oy) * 64 + t4;
    float4 r = *(const float4*)&yds[base];
    *(float4*)&out[base] = make_float4(acc[0][j] + r.x, acc[1][j] + r.y,
                                       acc[2][j] + r.z, acc[3][j] + r.w);
  }
}

// =============== launch ===============
extern "C" void kernel_launch(void* const* d_in, const int* in_sizes, int n_in,
                              void* d_out, int out_size, void* d_ws, size_t ws_size,
                              hipStream_t stream) {
  (void)in_sizes; (void)n_in; (void)out_size; (void)ws_size;
  const float* x        = (const float*)d_in[0];
  const float* conv_w   = (const float*)d_in[1];
  const float* conv_b   = (const float*)d_in[2];
  const float* bn_g     = (const float*)d_in[3];
  const float* bn_b     = (const float*)d_in[4];
  const float* bn_mean  = (const float*)d_in[5];
  const float* bn_var   = (const float*)d_in[6];
  const float* in_w     = (const float*)d_in[7];
  const float* conv1d_w = (const float*)d_in[8];
  const float* conv1d_b = (const float*)d_in[9];
  const float* xproj_w  = (const float*)d_in[10];
  const float* dtproj_w = (const float*)d_in[11];
  const float* dtproj_b = (const float*)d_in[12];
  const float* A_log    = (const float*)d_in[13];
  const float* Dp       = (const float*)d_in[14];
  const float* out_w    = (const float*)d_in[15];
  float* ws = (float*)d_ws;
  float* out = (float*)d_out;

  k0_prep<<<329, 256, 0, stream>>>(conv_w, conv_b, bn_g, bn_b, bn_mean, bn_var,
                                   xproj_w, ws);
  k0b_transpose<<<1024, 256, 0, stream>>>(x, (unsigned short*)(ws + OFF_XT));
  k1_conv_mfma<<<512, 256, 0, stream>>>((const unsigned short*)(ws + OFF_XT),
                                        (const unsigned short*)(ws + OFF_WBF),
                                        ws + OFF_BIAS2, ws + OFF_YDS);
  k2_inproj<<<2048, 256, 0, stream>>>(ws + OFF_YDS, in_w, ws + OFF_XPRE, ws + OFF_Z);
  k3_conv1d_silu<<<4096, 256, 0, stream>>>(ws + OFF_XPRE, conv1d_w, conv1d_b,
                                           ws + OFF_XIN);
  k4_xproj<<<256, 256, 0, stream>>>(ws + OFF_XIN, ws + OFF_XWT, ws + OFF_BC);
  k5a_scan1<<<512, 256, 0, stream>>>(ws + OFF_XIN, ws + OFF_BC, A_log,
                                     dtproj_w, dtproj_b, ws + OFF_S, ws + OFF_DSUM);
  k5b1_group<<<512, 256, 0, stream>>>(ws + OFF_S, ws + OFF_DSUM, A_log,
                                      ws + OFF_GS, ws + OFF_GD);
  k5b2_groupscan<<<64, 256, 0, stream>>>(ws + OFF_GS, ws + OFF_GD, A_log);
  k5c_scan2<<<512, 256, 0, stream>>>(ws + OFF_XIN, ws + OFF_BC, ws + OFF_Z,
                                     A_log, dtproj_w, dtproj_b, Dp, ws + OFF_S,
                                     ws + OFF_DSUM, ws + OFF_GS, ws + OFF_YACT);
  k6_outproj<<<256, 256, 0, stream>>>(ws + OFF_YACT, out_w, ws + OFF_YDS, out);
}

// Round 6
// 308.646 us; speedup vs baseline: 2.0418x; 1.0189x over previous
//
#include <hip/hip_runtime.h>
#include <math.h>

// ---------------- problem sizes ----------------
#define NB 4
#define LTOK 4096
#define DM 128
#define DI 256
#define NCH 256    // scan chunks
#define TCH 16     // steps per chunk
#define GSZ 16     // chunks per combine group
#define NG  16     // groups = NCH/GSZ

// ---------------- workspace layout (float offsets) ----------------
// mamba intermediates t-major: [b][t][e]
#define OFF_A2     0u          // A2 table [256d][16n] = -exp(A_log)*log2(e) (4096)
#define OFF_BIAS2  73728u      // folded conv+bn bias [128]
#define OFF_XWT    73856u      // xproj_w transposed [256k][40e] (10240)
#define OFF_YDS    84096u      // gelu output [4][128][64][64]   (2097152)
#define OFF_XPRE   2181248u    // [4][4096][256]; ALIASED: S[b][c][n][d] and yact
#define OFF_Z      6375552u    // [4][4096][256]
#define OFF_XIN    10569856u   // [4][4096][256]
#define OFF_BC     14764160u   // [4][4096][32]: 0-15 B, 16-31 C (524288)
#define OFF_DSUM   15288448u   // [4][256c][256d] (262144)
#define OFF_GS     15550592u   // [4][16g][16n][256d] (262144); becomes ginit
#define OFF_GD     15812736u   // [4][16g][256d] (16384)
#define OFF_XT     15829120u   // bf16 x transposed (k0b/k1); then delta bf16 [4][4096][256]
#define OFF_WBF    17926272u   // bf16 conv weights*bn_inv [128co][9tap][64ci] (36864)
#define OFF_YACT   OFF_XPRE
// total 17963136 floats = 71.9 MB (< proven 79.9 MB budget)

#define DEV __device__ __forceinline__
#define L2E 1.4426950408889634f

typedef short bh8 __attribute__((ext_vector_type(8)));   // 8 bf16 (4 VGPR)
typedef float f4v __attribute__((ext_vector_type(4)));

DEV float fast_silu(float v) {
  return v * __builtin_amdgcn_rcpf(1.f + __expf(-v));
}

DEV unsigned short f2bf(float f) {                       // round-to-nearest-even
  unsigned int u = __float_as_uint(f);
  u = (u + 0x7FFFu + ((u >> 16) & 1u)) >> 16;
  return (unsigned short)u;
}

DEV float bf2f(unsigned short us) {
  return __uint_as_float((unsigned int)us << 16);
}

// =============== K0: bf16 conv weights; xwt transpose; bias; A2 table ===============
__global__ __launch_bounds__(256) void k0_prep(
    const float* __restrict__ conv_w, const float* __restrict__ conv_b,
    const float* __restrict__ bn_g, const float* __restrict__ bn_b,
    const float* __restrict__ bn_mean, const float* __restrict__ bn_var,
    const float* __restrict__ xproj_w, const float* __restrict__ A_log,
    float* __restrict__ ws) {
  int i = blockIdx.x * 256 + threadIdx.x;
  if (i < 73728) {
    // wbf[co][tap][ci] = bf16(conv_w[co][ci][tap] * bn_inv[co])
    int ci = i & 63; int tap = (i >> 6) % 9; int co = i / 576;
    float inv = bn_g[co] * rsqrtf(bn_var[co] + 1e-5f);
    ((unsigned short*)(ws + OFF_WBF))[i] = f2bf(conv_w[co * 576 + ci * 9 + tap] * inv);
  } else if (i < 73856) {
    int co = i - 73728;
    float inv = bn_g[co] * rsqrtf(bn_var[co] + 1e-5f);
    ws[OFF_BIAS2 + co] = (conv_b[co] - bn_mean[co]) * inv + bn_b[co];
  } else if (i < 84096) {
    int j = i - 73856; int e = j % 40; int k = j / 40;
    ws[OFF_XWT + j] = xproj_w[e * 256 + k];
  } else if (i < 88192) {
    int j = i - 84096;                                   // j = d*16+n
    ws[OFF_A2 + j] = -__expf(A_log[j]) * L2E;
  }
}

// =============== K0b: transpose x -> xt[b][iy][ix][ci] bf16 ===============
__global__ __launch_bounds__(256) void k0b_transpose(
    const float* __restrict__ x, unsigned short* __restrict__ xt) {
  __shared__ float t[64][65];
  const int tid = threadIdx.x;
  const int ixh = blockIdx.x & 1;
  const int iy = (blockIdx.x >> 1) & 127;
  const int b = blockIdx.x >> 8;
  {
    const int ixl = tid & 63, cw = tid >> 6;
#pragma unroll 4
    for (int i = 0; i < 16; ++i) {
      int ci = cw * 16 + i;
      t[ci][ixl] = x[(((size_t)(b * 64 + ci) * 128) + iy) * 128 + ixh * 64 + ixl];
    }
  }
  __syncthreads();
  {
    const int cil = tid & 63, iw = tid >> 6;
    unsigned short* dst = xt + (((size_t)(b * 128 + iy) * 128) + ixh * 64) * 64;
#pragma unroll 4
    for (int i = 0; i < 16; ++i) {
      int ix = iw * 16 + i;
      dst[ix * 64 + cil] = f2bf(t[cil][ix]);
    }
  }
}

// =============== K1: conv3x3 s2 + BN + GELU via bf16 MFMA ===============
__global__ __launch_bounds__(256) void k1_conv_mfma(
    const unsigned short* __restrict__ xt, const unsigned short* __restrict__ wbf,
    const float* __restrict__ bias2, float* __restrict__ yds) {
  const int tid = threadIdx.x;
  const int lane = tid & 63;
  const int w = tid >> 6;
  const int col = lane & 15, quad = lane >> 4;
  const int cohalf = blockIdx.x & 1;
  const int oy = (blockIdx.x >> 1) & 63;
  const int b = blockIdx.x >> 7;
  const int co0 = cohalf * 64 + (w & 1) * 32;
  const int tok0 = (w >> 1) * 32;
  const int iy0 = 2 * oy - 1;
  const bh8 bzero = {};
  f4v acc[2][2];
#pragma unroll
  for (int mt = 0; mt < 2; ++mt)
#pragma unroll
    for (int nt = 0; nt < 2; ++nt) acc[mt][nt] = (f4v){0.f, 0.f, 0.f, 0.f};

  const unsigned short* ap0 = wbf + (size_t)(co0 + col) * 576;
  const unsigned short* ap1 = wbf + (size_t)(co0 + 16 + col) * 576;

  for (int tap = 0; tap < 9; ++tap) {
    const int kh = tap / 3, kw = tap - kh * 3;
    const int iy = iy0 + kh;
    const int ix0 = 2 * (tok0 + col) - 1 + kw;
    const int ix1 = ix0 + 32;
    const unsigned short* xrow = xt + (long)(b * 128 + iy) * 8192;
    const bool ok0 = (iy >= 0) && (ix0 >= 0);
    const bool ok1 = (iy >= 0);
#pragma unroll
    for (int kc = 0; kc < 2; ++kc) {
      const int cib = kc * 32 + quad * 8;
      bh8 a0 = *(const bh8*)&ap0[tap * 64 + cib];
      bh8 a1 = *(const bh8*)&ap1[tap * 64 + cib];
      bh8 b0 = *(const bh8*)&xrow[(long)ix0 * 64 + cib];
      bh8 b1 = *(const bh8*)&xrow[(long)ix1 * 64 + cib];
      if (!ok0) b0 = bzero;
      if (!ok1) b1 = bzero;
      acc[0][0] = __builtin_amdgcn_mfma_f32_16x16x32_bf16(a0, b0, acc[0][0], 0, 0, 0);
      acc[1][0] = __builtin_amdgcn_mfma_f32_16x16x32_bf16(a1, b0, acc[1][0], 0, 0, 0);
      acc[0][1] = __builtin_amdgcn_mfma_f32_16x16x32_bf16(a0, b1, acc[0][1], 0, 0, 0);
      acc[1][1] = __builtin_amdgcn_mfma_f32_16x16x32_bf16(a1, b1, acc[1][1], 0, 0, 0);
    }
  }
#pragma unroll
  for (int mt = 0; mt < 2; ++mt)
#pragma unroll
    for (int nt = 0; nt < 2; ++nt) {
      const int tok = tok0 + nt * 16 + col;
#pragma unroll
      for (int r = 0; r < 4; ++r) {
        const int co = co0 + mt * 16 + quad * 4 + r;
        float v = acc[mt][nt][r] + bias2[co];
        float g = 0.5f * v * (1.f + erff(v * 0.70710678118f));
        yds[(((size_t)(b * 128 + co) * 64) + oy) * 64 + tok] = g;
      }
    }
}

// =============== K2: in_proj GEMM -> t-major xpre, z ===============
__global__ __launch_bounds__(256) void k2_inproj(
    const float* __restrict__ yds, const float* __restrict__ in_w,
    float* __restrict__ xpre, float* __restrict__ z) {
  __shared__ __align__(16) float a_lds[64][68];
  __shared__ __align__(16) float w_lds[64][68];
  const int tid = threadIdx.x;
  const int et = blockIdx.x & 7;
  const int rowid = blockIdx.x >> 3;
  const int oy = rowid & 63, b = rowid >> 6;
  const int t4 = (tid & 15) * 4, e4 = (tid >> 4) * 4;
  float acc[4][4];
#pragma unroll
  for (int i = 0; i < 4; ++i)
#pragma unroll
    for (int j = 0; j < 4; ++j) acc[i][j] = 0.f;

  for (int kc = 0; kc < 2; ++kc) {
    __syncthreads();
    for (int idx = tid; idx < 1024; idx += 256) {
      int k = idx >> 4, tq = idx & 15;
      *(float4*)&a_lds[k][tq * 4] =
          *(const float4*)&yds[(((size_t)(b * 128 + kc * 64 + k) * 64) + oy) * 64 + tq * 4];
    }
    for (int idx = tid; idx < 1024; idx += 256) {
      int j = idx >> 4, kq = idx & 15;
      float4 v = *(const float4*)&in_w[(size_t)(et * 64 + j) * 128 + kc * 64 + kq * 4];
      w_lds[kq * 4 + 0][j] = v.x; w_lds[kq * 4 + 1][j] = v.y;
      w_lds[kq * 4 + 2][j] = v.z; w_lds[kq * 4 + 3][j] = v.w;
    }
    __syncthreads();
#pragma unroll 8
    for (int k = 0; k < 64; ++k) {
      float4 a4 = *(const float4*)&a_lds[k][t4];
      float4 b4 = *(const float4*)&w_lds[k][e4];
      float av[4] = {a4.x, a4.y, a4.z, a4.w};
      float bv[4] = {b4.x, b4.y, b4.z, b4.w};
#pragma unroll
      for (int i = 0; i < 4; ++i)
#pragma unroll
        for (int j = 0; j < 4; ++j) acc[i][j] = fmaf(av[i], bv[j], acc[i][j]);
    }
  }
  const int e0 = et * 64 + e4;
#pragma unroll
  for (int i = 0; i < 4; ++i) {
    int t = oy * 64 + t4 + i;
    float4 v = make_float4(acc[i][0], acc[i][1], acc[i][2], acc[i][3]);
    float* dst = (e0 < 256) ? (xpre + ((size_t)(b * 4096 + t)) * 256 + e0)
                            : (z + ((size_t)(b * 4096 + t)) * 256 + (e0 - 256));
    *(float4*)dst = v;
  }
}

// =============== K3: depthwise causal conv1d (k=4) + SiLU, t-major ===============
__global__ __launch_bounds__(256) void k3_conv1d_silu(
    const float* __restrict__ xpre, const float* __restrict__ w,
    const float* __restrict__ bvec, float* __restrict__ xin) {
  int i = blockIdx.x * 256 + threadIdx.x;
  int e4 = (i & 63) * 4;
  int t = (i >> 6) & 4095;
  int b = i >> 18;
  const float* base = xpre + (size_t)b * 4096 * 256;
  float4 zero = make_float4(0.f, 0.f, 0.f, 0.f);
  float4 r0 = (t >= 3) ? *(const float4*)&base[(size_t)(t - 3) * 256 + e4] : zero;
  float4 r1 = (t >= 2) ? *(const float4*)&base[(size_t)(t - 2) * 256 + e4] : zero;
  float4 r2 = (t >= 1) ? *(const float4*)&base[(size_t)(t - 1) * 256 + e4] : zero;
  float4 r3 = *(const float4*)&base[(size_t)t * 256 + e4];
  float4 w0 = *(const float4*)&w[(e4 + 0) * 4];
  float4 w1 = *(const float4*)&w[(e4 + 1) * 4];
  float4 w2 = *(const float4*)&w[(e4 + 2) * 4];
  float4 w3 = *(const float4*)&w[(e4 + 3) * 4];
  float4 bv = *(const float4*)&bvec[e4];
  float o0 = bv.x + w0.x * r0.x + w0.y * r1.x + w0.z * r2.x + w0.w * r3.x;
  float o1 = bv.y + w1.x * r0.y + w1.y * r1.y + w1.z * r2.y + w1.w * r3.y;
  float o2 = bv.z + w2.x * r0.z + w2.y * r1.z + w2.z * r2.z + w2.w * r3.z;
  float o3 = bv.w + w3.x * r0.w + w3.y * r1.w + w3.z * r2.w + w3.w * r3.w;
  *(float4*)&xin[((size_t)b * 4096 + t) * 256 + e4] =
      make_float4(fast_silu(o0), fast_silu(o1), fast_silu(o2), fast_silu(o3));
}

// =============== K4: x_proj GEMM + dt_proj + softplus -> delta bf16, bc, dsum ===============
__global__ __launch_bounds__(256) void k4_xproj(
    const float* __restrict__ xin, const float* __restrict__ xwt,
    const float* __restrict__ dtw, const float* __restrict__ dtb,
    unsigned short* __restrict__ delta, float* __restrict__ bc,
    float* __restrict__ dsum) {
  __shared__ float a_lds[128][65];     // [e][t] transposed
  __shared__ float xdbl[40][68];
  const int tid = threadIdx.x;
  const int t = tid & 63;
  const int wv = __builtin_amdgcn_readfirstlane(tid >> 6);
  const int tt = blockIdx.x & 63, b = blockIdx.x >> 6;
  const int t0 = tt * 64;
  float acc[10];
#pragma unroll
  for (int j = 0; j < 10; ++j) acc[j] = 0.f;

  for (int kh2 = 0; kh2 < 2; ++kh2) {
    __syncthreads();
    for (int idx = tid; idx < 2048; idx += 256) {
      int tl = idx >> 5; int e4 = (idx & 31) * 4;
      float4 v = *(const float4*)&xin[((size_t)(b * 4096 + t0 + tl)) * 256 + kh2 * 128 + e4];
      a_lds[e4 + 0][tl] = v.x; a_lds[e4 + 1][tl] = v.y;
      a_lds[e4 + 2][tl] = v.z; a_lds[e4 + 3][tl] = v.w;
    }
    __syncthreads();
#pragma unroll 4
    for (int k = 0; k < 128; ++k) {
      float av = a_lds[k][t];
      const float* wrow = &xwt[(kh2 * 128 + k) * 40 + wv * 10];
#pragma unroll
      for (int j = 0; j < 10; ++j) acc[j] = fmaf(av, wrow[j], acc[j]);
    }
  }
#pragma unroll
  for (int j = 0; j < 10; ++j) xdbl[wv * 10 + j][t] = acc[j];
  __syncthreads();

  // delta bf16 + per-16t dsum; thread = d
  {
    int d = tid;
    float4 wa = *(const float4*)&dtw[d * 8];
    float4 wb = *(const float4*)&dtw[d * 8 + 4];
    float bias = dtb[d];
    unsigned short* dst = delta + ((size_t)(b * 4096 + t0)) * 256 + d;
    float ds = 0.f;
#pragma unroll 4
    for (int tl = 0; tl < 64; ++tl) {
      float s = bias;
      s = fmaf(wa.x, xdbl[0][tl], s); s = fmaf(wa.y, xdbl[1][tl], s);
      s = fmaf(wa.z, xdbl[2][tl], s); s = fmaf(wa.w, xdbl[3][tl], s);
      s = fmaf(wb.x, xdbl[4][tl], s); s = fmaf(wb.y, xdbl[5][tl], s);
      s = fmaf(wb.z, xdbl[6][tl], s); s = fmaf(wb.w, xdbl[7][tl], s);
      float dl = fmaxf(s, 0.f) + log1pf(__expf(-fabsf(s)));   // stable softplus
      unsigned short us = f2bf(dl);
      dst[(size_t)tl * 256] = us;
      ds += bf2f(us);                 // dsum consistent with bf16-rounded delta
      if ((tl & 15) == 15) {
        dsum[((size_t)b * 256 + tt * 4 + (tl >> 4)) * 256 + d] = ds;
        ds = 0.f;
      }
    }
  }
  // B/C -> bc[b][t][32]
  for (int idx = tid; idx < 2048; idx += 256) {
    int tl = idx >> 5, col = idx & 31;
    bc[((size_t)(b * 4096 + t0 + tl)) * 32 + col] = xdbl[8 + col][tl];
  }
}

// =============== K5a: pass 1 -> S[b][c][n][d] chunk-local scan ===============
// S region aliases xpre (dead after k3). Thread = d; h[16] in registers.
__global__ __launch_bounds__(256) void k5a_scan1(
    const float* __restrict__ xin, const float* __restrict__ bc,
    const unsigned short* __restrict__ delta, const float* __restrict__ a2tab,
    float* __restrict__ S) {
  __shared__ __align__(16) float bct[TCH * 32];
  const int tid = threadIdx.x;
  const int d = tid;
  const int c = blockIdx.x & (NCH - 1), b = blockIdx.x >> 8;
  const int t0 = c * TCH;
  {
    const float* src = bc + (size_t)(b * 4096 + t0) * 32;
    for (int i = tid; i < TCH * 32; i += 256) bct[i] = src[i];
  }
  float A2[16];
#pragma unroll
  for (int j = 0; j < 4; ++j) {
    float4 a = *(const float4*)&a2tab[d * 16 + j * 4];
    A2[4 * j + 0] = a.x; A2[4 * j + 1] = a.y; A2[4 * j + 2] = a.z; A2[4 * j + 3] = a.w;
  }
  float h[16];
#pragma unroll
  for (int n = 0; n < 16; ++n) h[n] = 0.f;
  const unsigned short* pd = delta + (size_t)(b * 4096 + t0) * 256 + d;
  const float* px = xin + (size_t)(b * 4096 + t0) * 256 + d;
  __syncthreads();
#pragma unroll 4
  for (int i = 0; i < TCH; ++i) {
    float dl = bf2f(pd[(size_t)i * 256]);
    float xv = px[(size_t)i * 256];
    float dlx = dl * xv;
    const float* r = &bct[i * 32];
    float4 B0 = *(const float4*)&r[0];
    float4 B1 = *(const float4*)&r[4];
    float4 B2 = *(const float4*)&r[8];
    float4 B3 = *(const float4*)&r[12];
    float Bv[16] = {B0.x, B0.y, B0.z, B0.w, B1.x, B1.y, B1.z, B1.w,
                    B2.x, B2.y, B2.z, B2.w, B3.x, B3.y, B3.z, B3.w};
#pragma unroll
    for (int n = 0; n < 16; ++n)
      h[n] = fmaf(exp2f(dl * A2[n]), h[n], dlx * Bv[n]);
  }
  const size_t sbase = ((size_t)(b * NCH + c) * 16) * 256 + d;
#pragma unroll
  for (int n = 0; n < 16; ++n) S[sbase + (size_t)n * 256] = h[n];
}

// =============== K5b1: within-group combine (in-place exclusive prefix) ===============
__global__ __launch_bounds__(256) void k5b1_group(
    float* __restrict__ S, const float* __restrict__ dsum,
    const float* __restrict__ a2tab, float* __restrict__ Gs,
    float* __restrict__ Gd) {
  const int d = threadIdx.x;
  const int n = blockIdx.x & 15, g = (blockIdx.x >> 4) & (NG - 1),
            b = blockIdx.x >> 8;
  const float A2 = a2tab[d * 16 + n];
  float h = 0.f, cum = 0.f;
#pragma unroll 4
  for (int c16 = 0; c16 < GSZ; ++c16) {
    int c = g * GSZ + c16;
    size_t si = ((size_t)(b * NCH + c) * 16 + n) * 256 + d;
    float s = S[si];
    float dsv = dsum[((size_t)b * NCH + c) * 256 + d];
    float P = exp2f(A2 * dsv);
    S[si] = h;
    h = fmaf(P, h, s);
    cum += dsv;
  }
  Gs[((size_t)(b * NG + g) * 16 + n) * 256 + d] = h;
  if (n == 0) Gd[((size_t)b * NG + g) * 256 + d] = cum;
}

// =============== K5b2: scan group totals -> ginit in-place over Gs ===============
__global__ __launch_bounds__(256) void k5b2_groupscan(
    float* __restrict__ Gs, const float* __restrict__ Gd,
    const float* __restrict__ a2tab) {
  const int d = threadIdx.x;
  const int n = blockIdx.x & 15, b = blockIdx.x >> 4;
  const float A2 = a2tab[d * 16 + n];
  float h = 0.f;
#pragma unroll
  for (int g = 0; g < NG; ++g) {
    size_t gi = ((size_t)(b * NG + g) * 16 + n) * 256 + d;
    float s = Gs[gi];
    float P = exp2f(A2 * Gd[((size_t)b * NG + g) * 256 + d]);
    Gs[gi] = h;
    h = fmaf(P, h, s);
  }
}

// =============== K5c: pass 2 -> y, fused (+x*Dp)*silu(z) ===============
// sy aliases: reads hinit slice S(b,c) then overwrites same range with yact.
__global__ __launch_bounds__(256) void k5c_scan2(
    const float* __restrict__ xin, const float* __restrict__ bc,
    const unsigned short* __restrict__ delta, const float* __restrict__ z,
    const float* __restrict__ a2tab, const float* __restrict__ Dp,
    const float* __restrict__ dsum, const float* __restrict__ Gs,
    float* sy) {
  __shared__ __align__(16) float bct[TCH * 32];
  const int tid = threadIdx.x;
  const int d = tid;
  const int c = blockIdx.x & (NCH - 1), b = blockIdx.x >> 8;
  const int t0 = c * TCH;
  {
    const float* src = bc + (size_t)(b * 4096 + t0) * 32;
    for (int i = tid; i < TCH * 32; i += 256) bct[i] = src[i];
  }
  float A2[16];
#pragma unroll
  for (int j = 0; j < 4; ++j) {
    float4 a = *(const float4*)&a2tab[d * 16 + j * 4];
    A2[4 * j + 0] = a.x; A2[4 * j + 1] = a.y; A2[4 * j + 2] = a.z; A2[4 * j + 3] = a.w;
  }
  const float Dpd = Dp[d];
  const int g = c >> 4, c16 = c & 15;
  float dpref = 0.f;
  {
    const float* pds = dsum + ((size_t)b * NCH + g * GSZ) * 256 + d;
    for (int cc = 0; cc < c16; ++cc) dpref += pds[(size_t)cc * 256];
  }
  const size_t sbase = ((size_t)(b * NCH + c) * 16) * 256 + d;
  const size_t gbase = ((size_t)(b * NG + g) * 16) * 256 + d;
  float h[16];
#pragma unroll
  for (int n = 0; n < 16; ++n) {
    float gi = Gs[gbase + (size_t)n * 256];
    float hl = sy[sbase + (size_t)n * 256];
    h[n] = fmaf(exp2f(A2[n] * dpref), gi, hl);
  }
  const size_t base = (size_t)(b * 4096 + t0) * 256 + d;
  const unsigned short* pd = delta + base;
  const float* px = xin + base;
  const float* pz = z + base;
  float* py = sy + base;               // same addresses as sbase slice
  __syncthreads();                     // h reads complete before yact stores
#pragma unroll 4
  for (int i = 0; i < TCH; ++i) {
    float dl = bf2f(pd[(size_t)i * 256]);
    float xv = px[(size_t)i * 256];
    float zv = pz[(size_t)i * 256];
    float dlx = dl * xv;
    const float* r = &bct[i * 32];
    float4 B0 = *(const float4*)&r[0];
    float4 B1 = *(const float4*)&r[4];
    float4 B2 = *(const float4*)&r[8];
    float4 B3 = *(const float4*)&r[12];
    float4 C0 = *(const float4*)&r[16];
    float4 C1 = *(const float4*)&r[20];
    float4 C2 = *(const float4*)&r[24];
    float4 C3 = *(const float4*)&r[28];
    float Bv[16] = {B0.x, B0.y, B0.z, B0.w, B1.x, B1.y, B1.z, B1.w,
                    B2.x, B2.y, B2.z, B2.w, B3.x, B3.y, B3.z, B3.w};
    float Cv[16] = {C0.x, C0.y, C0.z, C0.w, C1.x, C1.y, C1.z, C1.w,
                    C2.x, C2.y, C2.z, C2.w, C3.x, C3.y, C3.z, C3.w};
    float y = 0.f;
#pragma unroll
    for (int n = 0; n < 16; ++n) {
      h[n] = fmaf(exp2f(dl * A2[n]), h[n], dlx * Bv[n]);
      y = fmaf(h[n], Cv[n], y);
    }
    py[(size_t)i * 256] = (y + xv * Dpd) * fast_silu(zv);
  }
}

// =============== K6: out_proj GEMM + residual ===============
__global__ __launch_bounds__(256) void k6_outproj(
    const float* __restrict__ yact, const float* __restrict__ out_w,
    const float* __restrict__ yds, float* __restrict__ out) {
  __shared__ __align__(16) float a_lds[64][68];
  __shared__ __align__(16) float w_lds[64][132];
  const int tid = threadIdx.x;
  const int oy = blockIdx.x & 63, b = blockIdx.x >> 6;
  const int t4 = (tid & 15) * 4, c8 = (tid >> 4) * 8;
  float acc[4][8];
#pragma unroll
  for (int i = 0; i < 4; ++i)
#pragma unroll
    for (int j = 0; j < 8; ++j) acc[i][j] = 0.f;

  for (int kc = 0; kc < 4; ++kc) {
    __syncthreads();
    for (int idx = tid; idx < 1024; idx += 256) {
      int tl = idx >> 4; int e4 = (idx & 15) * 4;
      float4 v = *(const float4*)&yact[((size_t)(b * 4096 + oy * 64 + tl)) * 256 + kc * 64 + e4];
      a_lds[e4 + 0][tl] = v.x; a_lds[e4 + 1][tl] = v.y;
      a_lds[e4 + 2][tl] = v.z; a_lds[e4 + 3][tl] = v.w;
    }
    for (int idx = tid; idx < 2048; idx += 256) {
      int cc = idx >> 4, kq = idx & 15;
      float4 v = *(const float4*)&out_w[(size_t)cc * 256 + kc * 64 + kq * 4];
      w_lds[kq * 4 + 0][cc] = v.x; w_lds[kq * 4 + 1][cc] = v.y;
      w_lds[kq * 4 + 2][cc] = v.z; w_lds[kq * 4 + 3][cc] = v.w;
    }
    __syncthreads();
#pragma unroll 4
    for (int k = 0; k < 64; ++k) {
      float4 a4 = *(const float4*)&a_lds[k][t4];
      float4 b0 = *(const float4*)&w_lds[k][c8];
      float4 b1 = *(const float4*)&w_lds[k][c8 + 4];
      float av[4] = {a4.x, a4.y, a4.z, a4.w};
      float bv[8] = {b0.x, b0.y, b0.z, b0.w, b1.x, b1.y, b1.z, b1.w};
#pragma unroll
      for (int i = 0; i < 4; ++i)
#pragma unroll
        for (int j = 0; j < 8; ++j) acc[i][j] = fmaf(av[i], bv[j], acc[i][j]);
    }
  }
#pragma unroll
  for (int j = 0; j < 8; ++j) {
    int cc = c8 + j;
    size_t base = (((size_t)(b * 128 + cc) * 64) + oy) * 64 + t4;
    float4 r = *(const float4*)&yds[base];
    *(float4*)&out[base] = make_float4(acc[0][j] + r.x, acc[1][j] + r.y,
                                       acc[2][j] + r.z, acc[3][j] + r.w);
  }
}

// =============== launch ===============
extern "C" void kernel_launch(void* const* d_in, const int* in_sizes, int n_in,
                              void* d_out, int out_size, void* d_ws, size_t ws_size,
                              hipStream_t stream) {
  (void)in_sizes; (void)n_in; (void)out_size; (void)ws_size;
  const float* x        = (const float*)d_in[0];
  const float* conv_w   = (const float*)d_in[1];
  const float* conv_b   = (const float*)d_in[2];
  const float* bn_g     = (const float*)d_in[3];
  const float* bn_b     = (const float*)d_in[4];
  const float* bn_mean  = (const float*)d_in[5];
  const float* bn_var   = (const float*)d_in[6];
  const float* in_w     = (const float*)d_in[7];
  const float* conv1d_w = (const float*)d_in[8];
  const float* conv1d_b = (const float*)d_in[9];
  const float* xproj_w  = (const float*)d_in[10];
  const float* dtproj_w = (const float*)d_in[11];
  const float* dtproj_b = (const float*)d_in[12];
  const float* A_log    = (const float*)d_in[13];
  const float* Dp       = (const float*)d_in[14];
  const float* out_w    = (const float*)d_in[15];
  float* ws = (float*)d_ws;
  float* out = (float*)d_out;

  k0_prep<<<345, 256, 0, stream>>>(conv_w, conv_b, bn_g, bn_b, bn_mean, bn_var,
                                   xproj_w, A_log, ws);
  k0b_transpose<<<1024, 256, 0, stream>>>(x, (unsigned short*)(ws + OFF_XT));
  k1_conv_mfma<<<512, 256, 0, stream>>>((const unsigned short*)(ws + OFF_XT),
                                        (const unsigned short*)(ws + OFF_WBF),
                                        ws + OFF_BIAS2, ws + OFF_YDS);
  k2_inproj<<<2048, 256, 0, stream>>>(ws + OFF_YDS, in_w, ws + OFF_XPRE, ws + OFF_Z);
  k3_conv1d_silu<<<4096, 256, 0, stream>>>(ws + OFF_XPRE, conv1d_w, conv1d_b,
                                           ws + OFF_XIN);
  k4_xproj<<<256, 256, 0, stream>>>(ws + OFF_XIN, ws + OFF_XWT, dtproj_w,
                                    dtproj_b, (unsigned short*)(ws + OFF_XT),
                                    ws + OFF_BC, ws + OFF_DSUM);
  k5a_scan1<<<1024, 256, 0, stream>>>(ws + OFF_XIN, ws + OFF_BC,
                                      (const unsigned short*)(ws + OFF_XT),
                                      ws + OFF_A2, ws + OFF_XPRE);
  k5b1_group<<<1024, 256, 0, stream>>>(ws + OFF_XPRE, ws + OFF_DSUM, ws + OFF_A2,
                                       ws + OFF_GS, ws + OFF_GD);
  k5b2_groupscan<<<64, 256, 0, stream>>>(ws + OFF_GS, ws + OFF_GD, ws + OFF_A2);
  k5c_scan2<<<1024, 256, 0, stream>>>(ws + OFF_XIN, ws + OFF_BC,
                                      (const unsigned short*)(ws + OFF_XT),
                                      ws + OFF_Z, ws + OFF_A2, Dp, ws + OFF_DSUM,
                                      ws + OFF_GS, ws + OFF_XPRE);
  k6_outproj<<<256, 256, 0, stream>>>(ws + OFF_YACT, out_w, ws + OFF_YDS, out);
}